// Round 6
// baseline (340.334 us; speedup 1.0000x reference)
//
#include <hip/hip_runtime.h>

#define NEG 0.2f

// ---------- bf16 pack/unpack (RNE) ----------
__device__ __forceinline__ float blo(unsigned u) { return __uint_as_float(u << 16); }
__device__ __forceinline__ float bhi(unsigned u) { return __uint_as_float(u & 0xffff0000u); }
__device__ __forceinline__ unsigned bpack(float a, float b) {
  unsigned ua = __float_as_uint(a), ub = __float_as_uint(b);
  unsigned ra = (ua + 0x7fffu + ((ua >> 16) & 1u)) >> 16;
  unsigned rb = (ub + 0x7fffu + ((ub >> 16) & 1u)) >> 16;
  return ra | (rb << 16);
}

// ---------- detect whether edge_index arrived as int64 or int32 ----------
__global__ void detect_idx64(const void* __restrict__ ei, int n_nodes, int* __restrict__ flag) {
  const long long* e64 = (const long long*)ei;
  long long v = e64[threadIdx.x];
  bool ok = (v >= 0 && v < (long long)n_nodes);
  unsigned long long b = __ballot(ok);
  if (threadIdx.x == 0) *flag = (b == ~0ull) ? 1 : 0;
}

__device__ __forceinline__ void get_edge(const void* __restrict__ ei, int is64, int e, int E,
                                         int& src, int& dst) {
  if (e >= E) { src = e - E; dst = e - E; return; }  // self-loops appended
  if (is64) {
    const long long* p = (const long long*)ei;
    src = (int)p[e];
    dst = (int)p[(size_t)E + e];
  } else {
    const int* p = (const int*)ei;
    src = p[e];
    dst = p[E + e];
  }
}

// ---------- CSR build: histogram -> scan -> scatter ----------
__global__ void hist_k(const void* __restrict__ ei, const int* __restrict__ flag,
                       int* __restrict__ count, int E, int Etot) {
  int e = blockIdx.x * 256 + threadIdx.x;
  if (e >= Etot) return;
  int src, dst;
  get_edge(ei, *flag, e, E, src, dst);
  (void)src;
  atomicAdd(&count[dst], 1);
}

__global__ void scan1_k(const int* __restrict__ count, int* __restrict__ bsum, int n) {
  __shared__ int sd[256];
  int i = blockIdx.x * 256 + threadIdx.x;
  sd[threadIdx.x] = (i < n) ? count[i] : 0;
  __syncthreads();
  for (int o = 128; o; o >>= 1) {
    if (threadIdx.x < o) sd[threadIdx.x] += sd[threadIdx.x + o];
    __syncthreads();
  }
  if (threadIdx.x == 0) bsum[blockIdx.x] = sd[0];
}

__global__ void scan2_k(int* __restrict__ bsum, int nb) {  // exclusive scan, 1 block, nb<=256
  __shared__ int sd[256];
  int v = (threadIdx.x < nb) ? bsum[threadIdx.x] : 0;
  sd[threadIdx.x] = v;
  __syncthreads();
  for (int o = 1; o < 256; o <<= 1) {
    int t = (threadIdx.x >= o) ? sd[threadIdx.x - o] : 0;
    __syncthreads();
    sd[threadIdx.x] += t;
    __syncthreads();
  }
  if (threadIdx.x < nb) bsum[threadIdx.x] = sd[threadIdx.x] - v;
}

__global__ void scan3_k(const int* __restrict__ count, const int* __restrict__ bsum,
                        int* __restrict__ off, int* __restrict__ cursor, int n, int etot) {
  __shared__ int sd[256];
  int i = blockIdx.x * 256 + threadIdx.x;
  int v = (i < n) ? count[i] : 0;
  sd[threadIdx.x] = v;
  __syncthreads();
  for (int o = 1; o < 256; o <<= 1) {
    int t = (threadIdx.x >= o) ? sd[threadIdx.x - o] : 0;
    __syncthreads();
    sd[threadIdx.x] += t;
    __syncthreads();
  }
  if (i < n) {
    int ex = bsum[blockIdx.x] + sd[threadIdx.x] - v;
    off[i] = ex;
    cursor[i] = ex;
  }
  if (i == 0) off[n] = etot;
}

__global__ void scatter_k(const void* __restrict__ ei, const int* __restrict__ flag,
                          int* __restrict__ cursor, int* __restrict__ bsrc,
                          int* __restrict__ bdst, int E, int Etot) {
  int e = blockIdx.x * 256 + threadIdx.x;
  if (e >= Etot) return;
  int src, dst;
  get_edge(ei, *flag, e, E, src, dst);
  int pos = atomicAdd(&cursor[dst], 1);
  bsrc[pos] = src;
  bdst[pos] = dst;
}

// ---------- tiled dual GEMM with packed-pair bf16 epilogue ----------
// [xl|xr] = X @ [Wl|Wr], K=128. Output written as packed bf16 pairs:
// out_p[row][q] = pack(col_a(q), col_a(q)+HS/2), col_a(q) = (q/(HS/2))*HS + q%(HS/2).
template <int C, int TM, int TCG, int RPT, int HS>
__global__ void dual_gemm_p(const float* __restrict__ X,
                            const float* __restrict__ Wl,
                            const float* __restrict__ Wr,
                            unsigned* __restrict__ xl_p, unsigned* __restrict__ xr_p, int nrows) {
  constexpr int K = 128, KT = 32, W2 = 2 * C, NPM = C / 2, PS = HS / 2;
  __shared__ float xsT[KT][TM];   // transposed X tile
  __shared__ float ws[KT][W2];    // [Wl | Wr] tile
  const int tid = threadIdx.x;
  const int tc = tid % TCG, tr = tid / TCG;
  const int row0 = blockIdx.x * TM;
  const int mat = (4 * tc) / NPM;          // 0 -> xl, 1 -> xr
  const int q0 = (4 * tc) % NPM;           // pair index within matrix
  const int col_a0 = mat * C + (q0 / PS) * HS + (q0 % PS);
  float acc[RPT][8] = {};

  for (int k0 = 0; k0 < K; k0 += KT) {
    constexpr int XF4 = TM * KT / 4 / 256;
#pragma unroll
    for (int i = 0; i < XF4; ++i) {
      int f = tid + i * 256;
      int row = f / (KT / 4), j = f % (KT / 4);
      float4 v = make_float4(0.f, 0.f, 0.f, 0.f);
      if (row0 + row < nrows) v = *(const float4*)&X[(size_t)(row0 + row) * K + k0 + 4 * j];
      xsT[4 * j + 0][row] = v.x;
      xsT[4 * j + 1][row] = v.y;
      xsT[4 * j + 2][row] = v.z;
      xsT[4 * j + 3][row] = v.w;
    }
    constexpr int WF4 = KT * C / 4 / 256;
#pragma unroll
    for (int i = 0; i < WF4; ++i) {
      int f = tid + i * 256;
      int kk = f / (C / 4), c4 = f % (C / 4);
      *(float4*)&ws[kk][c4 * 4]     = *(const float4*)&Wl[(size_t)(k0 + kk) * C + c4 * 4];
      *(float4*)&ws[kk][C + c4 * 4] = *(const float4*)&Wr[(size_t)(k0 + kk) * C + c4 * 4];
    }
    __syncthreads();
#pragma unroll 4
    for (int kk = 0; kk < KT; ++kk) {
      float xv[RPT], wv[8];
#pragma unroll
      for (int i = 0; i < RPT; i += 4) *(float4*)&xv[i] = *(const float4*)&xsT[kk][tr * RPT + i];
      *(float4*)&wv[0] = *(const float4*)&ws[kk][col_a0];
      *(float4*)&wv[4] = *(const float4*)&ws[kk][col_a0 + PS];
#pragma unroll
      for (int i = 0; i < RPT; ++i)
#pragma unroll
        for (int j = 0; j < 8; ++j) acc[i][j] = fmaf(xv[i], wv[j], acc[i][j]);
    }
    __syncthreads();
  }

  unsigned* outp = (mat == 0) ? xl_p : xr_p;
#pragma unroll
  for (int i = 0; i < RPT; ++i) {
    int row = row0 + tr * RPT + i;
    if (row >= nrows) break;
    uint4 u;
    u.x = bpack(acc[i][0], acc[i][4]);
    u.y = bpack(acc[i][1], acc[i][5]);
    u.z = bpack(acc[i][2], acc[i][6]);
    u.w = bpack(acc[i][3], acc[i][7]);
    *(uint4*)&outp[(size_t)row * NPM + q0] = u;
  }
}

// ---------- layer 1 pass A: per-edge, per-HEAD logits (float2), no cross-lane ----------
// Pair layout: q<32 -> head0 channels (q, q+32); q>=32 -> head1 channels (q%32, q%32+32).
__global__ void edge_logits1_k(const unsigned* __restrict__ xl_p, const unsigned* __restrict__ xr_p,
                               const int* __restrict__ bsrc, const int* __restrict__ bdst,
                               const float* __restrict__ att, float2* __restrict__ logits2, int Etot) {
  int e = blockIdx.x * 256 + threadIdx.x;
  if (e >= Etot) return;
  int src = bsrc[e], dst = bdst[e];
  const uint4* pl = (const uint4*)(xl_p + (size_t)src * 64);
  const uint4* pr = (const uint4*)(xr_p + (size_t)dst * 64);
  float t0a = 0.f, t0b = 0.f, t1a = 0.f, t1b = 0.f;
#pragma unroll
  for (int i = 0; i < 16; ++i) {
    int h = i / 8;                   // head of this uint4 (q = 4i..4i+3)
    uint4 ul = pl[i];
    uint4 ur = pr[i];
    unsigned la[4] = {ul.x, ul.y, ul.z, ul.w};
    unsigned ra[4] = {ur.x, ur.y, ur.z, ur.w};
#pragma unroll
    for (int k = 0; k < 4; ++k) {
      int c = (4 * i + k) % 32;      // pair index within head
      float ea = blo(la[k]) + blo(ra[k]); ea = fmaxf(ea, NEG * ea);
      float eb = bhi(la[k]) + bhi(ra[k]); eb = fmaxf(eb, NEG * eb);
      float contrib_hi = eb * att[h * 64 + c + 32];
      if (h == 0) {
        if (k & 1) t0b = fmaf(ea, att[c], contrib_hi + t0b);
        else       t0a = fmaf(ea, att[c], contrib_hi + t0a);
      } else {
        if (k & 1) t1b = fmaf(ea, att[64 + c], contrib_hi + t1b);
        else       t1a = fmaf(ea, att[64 + c], contrib_hi + t1a);
      }
    }
  }
  logits2[e] = make_float2(t0a + t0b, t1a + t1b);
}

// ---------- layer 1 pass B: wave per node, per-head softmax ----------
__global__ void aggregate1_k(const unsigned* __restrict__ xl_p,
                             const int* __restrict__ off, const int* __restrict__ bsrc,
                             const float2* __restrict__ logits2,
                             const float* __restrict__ b, float* __restrict__ h1, int N) {
  __shared__ float4 stash_all[4][64];
  int g = threadIdx.x >> 6;
  int lane = threadIdx.x & 63;
  int node = blockIdx.x * 4 + g;
  if (node >= N) return;
  float4* stash = stash_all[g];
  int j0 = off[node], jend = off[node + 1];

  // pass 1: per-head segment max (full-wave butterflies)
  float m0 = -INFINITY, m1 = -INFINITY;
  for (int c = j0; c < jend; c += 64) {
    int idx = c + lane;
    float2 tv = (idx < jend) ? logits2[idx] : make_float2(-INFINITY, -INFINITY);
    m0 = fmaxf(m0, tv.x);
    m1 = fmaxf(m1, tv.y);
  }
#pragma unroll
  for (int o = 1; o < 64; o <<= 1) {
    m0 = fmaxf(m0, __shfl_xor(m0, o));
    m1 = fmaxf(m1, __shfl_xor(m1, o));
  }

  // pass 2: p = exp(t - m) per head, stash (p0, p1, src), gather-accumulate
  float s0 = 0.f, s1 = 0.f, oa = 0.f, ob = 0.f;
  for (int c = j0; c < jend; c += 64) {
    int idx = c + lane;
    float2 tv = (idx < jend) ? logits2[idx] : make_float2(-INFINITY, -INFINITY);
    float p0 = __expf(tv.x - m0);          // 0 for masked lanes
    float p1 = __expf(tv.y - m1);
    s0 += p0;
    s1 += p1;
    int srcv = bsrc[idx];                  // bsrc padded by 64 -> safe
    stash[lane] = make_float4(p0, p1, __int_as_float(srcv), 0.f);
    int nch = (jend - c < 64) ? (jend - c) : 64;
    int j = 0;
    for (; j + 1 < nch; j += 2) {
      float4 ps0 = stash[j];
      float4 ps1 = stash[j + 1];
      float pw0 = (lane < 32) ? ps0.x : ps0.y;
      float pw1 = (lane < 32) ? ps1.x : ps1.y;
      unsigned u0 = xl_p[(size_t)__float_as_int(ps0.z) * 64 + lane];
      unsigned u1 = xl_p[(size_t)__float_as_int(ps1.z) * 64 + lane];
      oa = fmaf(pw0, blo(u0), oa);
      ob = fmaf(pw0, bhi(u0), ob);
      oa = fmaf(pw1, blo(u1), oa);
      ob = fmaf(pw1, bhi(u1), ob);
    }
    if (j < nch) {
      float4 ps0 = stash[j];
      float pw0 = (lane < 32) ? ps0.x : ps0.y;
      unsigned u0 = xl_p[(size_t)__float_as_int(ps0.z) * 64 + lane];
      oa = fmaf(pw0, blo(u0), oa);
      ob = fmaf(pw0, bhi(u0), ob);
    }
  }
#pragma unroll
  for (int o = 1; o < 64; o <<= 1) {
    s0 += __shfl_xor(s0, o);
    s1 += __shfl_xor(s1, o);
  }

  float inv = 1.f / ((lane < 32) ? s0 : s1);
  int ch_a = (lane < 32) ? lane : 32 + lane;   // head0: (l, l+32); head1: (64+l', 96+l')
  int ch_b = ch_a + 32;
  float ra = fmaf(oa, inv, b[ch_a]);
  float rb = fmaf(ob, inv, b[ch_b]);
  h1[(size_t)node * 128 + ch_a] = ra > 0.f ? ra : __expf(ra) - 1.f;  // ELU
  h1[(size_t)node * 128 + ch_b] = rb > 0.f ? rb : __expf(rb) - 1.f;
}

// ---------- layer 2 pass A: per-edge scalar logit (H=1) ----------
__global__ void edge_logits2_k(const unsigned* __restrict__ xl_p, const unsigned* __restrict__ xr_p,
                               const int* __restrict__ bsrc, const int* __restrict__ bdst,
                               const float* __restrict__ att, float* __restrict__ logits, int Etot) {
  int e = blockIdx.x * 256 + threadIdx.x;
  if (e >= Etot) return;
  int src = bsrc[e], dst = bdst[e];
  const uint4* pl = (const uint4*)(xl_p + (size_t)src * 16);
  const uint4* pr = (const uint4*)(xr_p + (size_t)dst * 16);
  float t0 = 0.f, t1 = 0.f;
#pragma unroll
  for (int i = 0; i < 4; ++i) {
    uint4 ul = pl[i];
    uint4 ur = pr[i];
    unsigned la[4] = {ul.x, ul.y, ul.z, ul.w};
    unsigned ra[4] = {ur.x, ur.y, ur.z, ur.w};
#pragma unroll
    for (int k = 0; k < 4; ++k) {
      int c = 4 * i + k;                  // pair -> channels (c, c+16)
      float ea = blo(la[k]) + blo(ra[k]); ea = fmaxf(ea, NEG * ea);
      float eb = bhi(la[k]) + bhi(ra[k]); eb = fmaxf(eb, NEG * eb);
      if (k & 1) t1 = fmaf(ea, att[c], fmaf(eb, att[c + 16], t1));
      else       t0 = fmaf(ea, att[c], fmaf(eb, att[c + 16], t0));
    }
  }
  logits[e] = t0 + t1;
}

// ---------- layer 2 pass B: 16 lanes per node ----------
__global__ void aggregate2_k(const unsigned* __restrict__ xl_p,
                             const int* __restrict__ off, const int* __restrict__ bsrc,
                             const float* __restrict__ logits,
                             const float* __restrict__ b, float* __restrict__ out, int N) {
  __shared__ float2 stash_all[16][16];
  int g = threadIdx.x >> 4;
  int lane = threadIdx.x & 15;
  int node = blockIdx.x * 16 + g;
  if (node >= N) return;
  float2* stash = stash_all[g];
  int j0 = off[node], jend = off[node + 1];

  float mt = -INFINITY;
  for (int c = j0; c < jend; c += 16) {
    int idx = c + lane;
    float tv = (idx < jend) ? logits[idx] : -INFINITY;
    mt = fmaxf(mt, tv);
  }
#pragma unroll
  for (int o = 1; o < 16; o <<= 1) mt = fmaxf(mt, __shfl_xor(mt, o));

  float s = 0.f, oa = 0.f, ob = 0.f;
  for (int c = j0; c < jend; c += 16) {
    int idx = c + lane;
    float tv = (idx < jend) ? logits[idx] : -INFINITY;
    float p = __expf(tv - mt);
    s += p;
    int srcv = bsrc[idx];
    stash[lane] = make_float2(p, __int_as_float(srcv));
    int nch = (jend - c < 16) ? (jend - c) : 16;
    int j = 0;
    for (; j + 1 < nch; j += 2) {
      float2 ps0 = stash[j];
      float2 ps1 = stash[j + 1];
      unsigned u0 = xl_p[(size_t)__float_as_int(ps0.y) * 16 + lane];
      unsigned u1 = xl_p[(size_t)__float_as_int(ps1.y) * 16 + lane];
      oa = fmaf(ps0.x, blo(u0), oa);
      ob = fmaf(ps0.x, bhi(u0), ob);
      oa = fmaf(ps1.x, blo(u1), oa);
      ob = fmaf(ps1.x, bhi(u1), ob);
    }
    if (j < nch) {
      float2 ps0 = stash[j];
      unsigned u0 = xl_p[(size_t)__float_as_int(ps0.y) * 16 + lane];
      oa = fmaf(ps0.x, blo(u0), oa);
      ob = fmaf(ps0.x, bhi(u0), ob);
    }
  }
#pragma unroll
  for (int o = 1; o < 16; o <<= 1) s += __shfl_xor(s, o);

  float inv = 1.f / s;
  out[(size_t)node * 32 + lane]      = fmaf(oa, inv, b[lane]);
  out[(size_t)node * 32 + 16 + lane] = fmaf(ob, inv, b[lane + 16]);
}

extern "C" void kernel_launch(void* const* d_in, const int* in_sizes, int n_in,
                              void* d_out, int out_size, void* d_ws, size_t ws_size,
                              hipStream_t stream) {
  const float* x    = (const float*)d_in[0];
  const void*  ei   = d_in[1];
  const float* Wl1  = (const float*)d_in[2];
  const float* Wr1  = (const float*)d_in[3];
  const float* att1 = (const float*)d_in[4];
  const float* b1   = (const float*)d_in[5];
  const float* Wl2  = (const float*)d_in[6];
  const float* Wr2  = (const float*)d_in[7];
  const float* att2 = (const float*)d_in[8];
  const float* b2   = (const float*)d_in[9];

  const int N = in_sizes[0] / 128;
  const int E = in_sizes[1] / 2;
  const int Etot = E + N;
  float* out = (float*)d_out;
  (void)out_size; (void)n_in; (void)ws_size;

  // ---------------- workspace layout ----------------
  char* ws = (char*)d_ws;
  size_t off_b = 0;
  auto alloc = [&](size_t bytes) {
    void* p = ws + off_b;
    off_b += (bytes + 255) & ~(size_t)255;
    return p;
  };
  unsigned* xl1p    = (unsigned*)alloc((size_t)N * 64 * 4);  // packed bf16 pairs
  unsigned* xr1p    = (unsigned*)alloc((size_t)N * 64 * 4);
  float*    h1      = (float*)alloc((size_t)N * 128 * 4);
  int*      bsrc    = (int*)alloc((size_t)(Etot + 64) * 4);  // padded for masked reads
  int*      bdst    = (int*)alloc((size_t)(Etot + 64) * 4);
  float2*   logits2 = (float2*)alloc((size_t)Etot * 8);      // layer1: per-head logits
  int*      csroff  = (int*)alloc((size_t)(N + 1) * 4);
  int*      cursor  = (int*)alloc((size_t)N * 4);
  int*      count   = (int*)alloc((size_t)N * 4);
  int*      bsum    = (int*)alloc(256 * 4);
  int*      flag    = (int*)alloc(256);

  // layer-2 packed transforms overlay the (then-dead) xl1p region; scalar logits reuse logits2
  unsigned* xl2p = xl1p;
  unsigned* xr2p = xl1p + (size_t)N * 16;
  float*    logits = (float*)logits2;

  const int nscan = (N + 255) / 256;  // <= 256 blocks
  const int eblk = (Etot + 255) / 256;

  // ---------------- CSR build (shared by both layers) ----------------
  hipLaunchKernelGGL(detect_idx64, dim3(1), dim3(64), 0, stream, ei, N, flag);
  hipMemsetAsync(count, 0, (size_t)N * 4, stream);
  hipLaunchKernelGGL(hist_k, dim3(eblk), dim3(256), 0, stream, ei, flag, count, E, Etot);
  hipLaunchKernelGGL(scan1_k, dim3(nscan), dim3(256), 0, stream, count, bsum, N);
  hipLaunchKernelGGL(scan2_k, dim3(1), dim3(256), 0, stream, bsum, nscan);
  hipLaunchKernelGGL(scan3_k, dim3(nscan), dim3(256), 0, stream, count, bsum, csroff, cursor, N, Etot);
  hipLaunchKernelGGL(scatter_k, dim3(eblk), dim3(256), 0, stream, ei, flag, cursor, bsrc, bdst, E, Etot);

  // ---------------- layer 1 ----------------
  hipLaunchKernelGGL((dual_gemm_p<128, 64, 32, 8, 64>), dim3((N + 63) / 64), dim3(256), 0, stream,
                     x, Wl1, Wr1, xl1p, xr1p, N);
  hipLaunchKernelGGL(edge_logits1_k, dim3(eblk), dim3(256), 0, stream,
                     xl1p, xr1p, bsrc, bdst, att1, logits2, Etot);
  hipLaunchKernelGGL(aggregate1_k, dim3((N + 3) / 4), dim3(256), 0, stream,
                     xl1p, csroff, bsrc, logits2, b1, h1, N);

  // ---------------- layer 2 ----------------
  hipLaunchKernelGGL((dual_gemm_p<32, 128, 8, 4, 32>), dim3((N + 127) / 128), dim3(256), 0, stream,
                     h1, Wl2, Wr2, xl2p, xr2p, N);
  hipLaunchKernelGGL(edge_logits2_k, dim3(eblk), dim3(256), 0, stream,
                     xl2p, xr2p, bsrc, bdst, att2, logits, Etot);
  hipLaunchKernelGGL(aggregate2_k, dim3((N + 15) / 16), dim3(256), 0, stream,
                     xl2p, csroff, bsrc, logits, b2, out, N);
}

// Round 7
// 272.466 us; speedup vs baseline: 1.2491x; 1.2491x over previous
//
#include <hip/hip_runtime.h>

#define NEG 0.2f

// ---------- bf16 pack/unpack (RNE) ----------
__device__ __forceinline__ float blo(unsigned u) { return __uint_as_float(u << 16); }
__device__ __forceinline__ float bhi(unsigned u) { return __uint_as_float(u & 0xffff0000u); }
__device__ __forceinline__ unsigned bpack(float a, float b) {
  unsigned ua = __float_as_uint(a), ub = __float_as_uint(b);
  unsigned ra = (ua + 0x7fffu + ((ua >> 16) & 1u)) >> 16;
  unsigned rb = (ub + 0x7fffu + ((ub >> 16) & 1u)) >> 16;
  return ra | (rb << 16);
}

// ---------- detect whether edge_index arrived as int64 or int32 ----------
__global__ void detect_idx64(const void* __restrict__ ei, int n_nodes, int* __restrict__ flag) {
  const long long* e64 = (const long long*)ei;
  long long v = e64[threadIdx.x];
  bool ok = (v >= 0 && v < (long long)n_nodes);
  unsigned long long b = __ballot(ok);
  if (threadIdx.x == 0) *flag = (b == ~0ull) ? 1 : 0;
}

__device__ __forceinline__ void get_edge(const void* __restrict__ ei, int is64, int e, int E,
                                         int& src, int& dst) {
  if (e >= E) { src = e - E; dst = e - E; return; }  // self-loops appended
  if (is64) {
    const long long* p = (const long long*)ei;
    src = (int)p[e];
    dst = (int)p[(size_t)E + e];
  } else {
    const int* p = (const int*)ei;
    src = p[e];
    dst = p[E + e];
  }
}

// ---------- CSR build: histogram -> scan -> scatter ----------
__global__ void hist_k(const void* __restrict__ ei, const int* __restrict__ flag,
                       int* __restrict__ count, int E, int Etot) {
  int e = blockIdx.x * 256 + threadIdx.x;
  if (e >= Etot) return;
  int src, dst;
  get_edge(ei, *flag, e, E, src, dst);
  (void)src;
  atomicAdd(&count[dst], 1);
}

__global__ void scan1_k(const int* __restrict__ count, int* __restrict__ bsum, int n) {
  __shared__ int sd[256];
  int i = blockIdx.x * 256 + threadIdx.x;
  sd[threadIdx.x] = (i < n) ? count[i] : 0;
  __syncthreads();
  for (int o = 128; o; o >>= 1) {
    if (threadIdx.x < o) sd[threadIdx.x] += sd[threadIdx.x + o];
    __syncthreads();
  }
  if (threadIdx.x == 0) bsum[blockIdx.x] = sd[0];
}

__global__ void scan2_k(int* __restrict__ bsum, int nb) {  // exclusive scan, 1 block, nb<=256
  __shared__ int sd[256];
  int v = (threadIdx.x < nb) ? bsum[threadIdx.x] : 0;
  sd[threadIdx.x] = v;
  __syncthreads();
  for (int o = 1; o < 256; o <<= 1) {
    int t = (threadIdx.x >= o) ? sd[threadIdx.x - o] : 0;
    __syncthreads();
    sd[threadIdx.x] += t;
    __syncthreads();
  }
  if (threadIdx.x < nb) bsum[threadIdx.x] = sd[threadIdx.x] - v;
}

__global__ void scan3_k(const int* __restrict__ count, const int* __restrict__ bsum,
                        int* __restrict__ off, int* __restrict__ cursor, int n, int etot) {
  __shared__ int sd[256];
  int i = blockIdx.x * 256 + threadIdx.x;
  int v = (i < n) ? count[i] : 0;
  sd[threadIdx.x] = v;
  __syncthreads();
  for (int o = 1; o < 256; o <<= 1) {
    int t = (threadIdx.x >= o) ? sd[threadIdx.x - o] : 0;
    __syncthreads();
    sd[threadIdx.x] += t;
    __syncthreads();
  }
  if (i < n) {
    int ex = bsum[blockIdx.x] + sd[threadIdx.x] - v;
    off[i] = ex;
    cursor[i] = ex;
  }
  if (i == 0) off[n] = etot;
}

__global__ void scatter_k(const void* __restrict__ ei, const int* __restrict__ flag,
                          int* __restrict__ cursor, int* __restrict__ bucket, int E, int Etot) {
  int e = blockIdx.x * 256 + threadIdx.x;
  if (e >= Etot) return;
  int src, dst;
  get_edge(ei, *flag, e, E, src, dst);
  int pos = atomicAdd(&cursor[dst], 1);
  bucket[pos] = src;
}

// ---------- tiled dual GEMM with packed-pair bf16 epilogue ----------
// [xl|xr] = X @ [Wl|Wr], K=128. Output written as packed bf16 pairs:
// out_p[row][q] = pack(col_a(q), col_a(q)+HS/2), col_a(q) = (q/(HS/2))*HS + q%(HS/2).
template <int C, int TM, int TCG, int RPT, int HS>
__global__ void dual_gemm_p(const float* __restrict__ X,
                            const float* __restrict__ Wl,
                            const float* __restrict__ Wr,
                            unsigned* __restrict__ xl_p, unsigned* __restrict__ xr_p, int nrows) {
  constexpr int K = 128, KT = 32, W2 = 2 * C, NPM = C / 2, PS = HS / 2;
  __shared__ float xsT[KT][TM];   // transposed X tile
  __shared__ float ws[KT][W2];    // [Wl | Wr] tile
  const int tid = threadIdx.x;
  const int tc = tid % TCG, tr = tid / TCG;
  const int row0 = blockIdx.x * TM;
  const int mat = (4 * tc) / NPM;          // 0 -> xl, 1 -> xr
  const int q0 = (4 * tc) % NPM;           // pair index within matrix
  const int col_a0 = mat * C + (q0 / PS) * HS + (q0 % PS);
  float acc[RPT][8] = {};

  for (int k0 = 0; k0 < K; k0 += KT) {
    constexpr int XF4 = TM * KT / 4 / 256;
#pragma unroll
    for (int i = 0; i < XF4; ++i) {
      int f = tid + i * 256;
      int row = f / (KT / 4), j = f % (KT / 4);
      float4 v = make_float4(0.f, 0.f, 0.f, 0.f);
      if (row0 + row < nrows) v = *(const float4*)&X[(size_t)(row0 + row) * K + k0 + 4 * j];
      xsT[4 * j + 0][row] = v.x;
      xsT[4 * j + 1][row] = v.y;
      xsT[4 * j + 2][row] = v.z;
      xsT[4 * j + 3][row] = v.w;
    }
    constexpr int WF4 = KT * C / 4 / 256;
#pragma unroll
    for (int i = 0; i < WF4; ++i) {
      int f = tid + i * 256;
      int kk = f / (C / 4), c4 = f % (C / 4);
      *(float4*)&ws[kk][c4 * 4]     = *(const float4*)&Wl[(size_t)(k0 + kk) * C + c4 * 4];
      *(float4*)&ws[kk][C + c4 * 4] = *(const float4*)&Wr[(size_t)(k0 + kk) * C + c4 * 4];
    }
    __syncthreads();
#pragma unroll 4
    for (int kk = 0; kk < KT; ++kk) {
      float xv[RPT], wv[8];
#pragma unroll
      for (int i = 0; i < RPT; i += 4) *(float4*)&xv[i] = *(const float4*)&xsT[kk][tr * RPT + i];
      *(float4*)&wv[0] = *(const float4*)&ws[kk][col_a0];
      *(float4*)&wv[4] = *(const float4*)&ws[kk][col_a0 + PS];
#pragma unroll
      for (int i = 0; i < RPT; ++i)
#pragma unroll
        for (int j = 0; j < 8; ++j) acc[i][j] = fmaf(xv[i], wv[j], acc[i][j]);
    }
    __syncthreads();
  }

  unsigned* outp = (mat == 0) ? xl_p : xr_p;
#pragma unroll
  for (int i = 0; i < RPT; ++i) {
    int row = row0 + tr * RPT + i;
    if (row >= nrows) break;
    uint4 u;
    u.x = bpack(acc[i][0], acc[i][4]);
    u.y = bpack(acc[i][1], acc[i][5]);
    u.z = bpack(acc[i][2], acc[i][6]);
    u.w = bpack(acc[i][3], acc[i][7]);
    *(uint4*)&outp[(size_t)row * NPM + q0] = u;
  }
}

// ---------- layer 1 fused: wave per node, head-split half-waves ----------
// Lane l<32: head0 pair (l, l+32); lane l>=32: head1 pair (32+l, 64+l).
// 2-edge batched online softmax + software-pipelined gather.
__global__ void fused_layer1_k(const unsigned* __restrict__ xl_p, const unsigned* __restrict__ xr_p,
                               const int* __restrict__ off, const int* __restrict__ bucket,
                               const float* __restrict__ att, const float* __restrict__ b,
                               float* __restrict__ h1, int N) {
  int node = blockIdx.x * 4 + (threadIdx.x >> 6);
  int lane = threadIdx.x & 63;
  if (node >= N) return;
  int ch_a = (lane < 32) ? lane : 32 + lane;
  int ch_b = ch_a + 32;
  unsigned xru = xr_p[(size_t)node * 64 + lane];
  float xr_a = blo(xru), xr_b = bhi(xru);
  float att_a = att[ch_a], att_b = att[ch_b];
  float m = -INFINITY, s = 0.f, oa = 0.f, ob = 0.f;
  int j0 = off[node], jend = off[node + 1];

  auto upd1 = [&](unsigned vu) {
    float va = blo(vu), vb = bhi(vu);
    float ea = va + xr_a; ea = fmaxf(ea, NEG * ea);
    float eb = vb + xr_b; eb = fmaxf(eb, NEG * eb);
    float t = fmaf(ea, att_a, eb * att_b);
#pragma unroll
    for (int o = 1; o < 32; o <<= 1) t += __shfl_xor(t, o);
    float nm = fmaxf(m, t);
    float c = __expf(m - nm), p = __expf(t - nm);
    s = fmaf(s, c, p);
    oa = fmaf(oa, c, p * va);
    ob = fmaf(ob, c, p * vb);
    m = nm;
  };

  auto upd2 = [&](unsigned ua, unsigned ub) {
    float va0 = blo(ua), va1 = bhi(ua);
    float vb0 = blo(ub), vb1 = bhi(ub);
    float ea0 = va0 + xr_a; ea0 = fmaxf(ea0, NEG * ea0);
    float ea1 = va1 + xr_b; ea1 = fmaxf(ea1, NEG * ea1);
    float eb0 = vb0 + xr_a; eb0 = fmaxf(eb0, NEG * eb0);
    float eb1 = vb1 + xr_b; eb1 = fmaxf(eb1, NEG * eb1);
    float ta = fmaf(ea0, att_a, ea1 * att_b);
    float tb = fmaf(eb0, att_a, eb1 * att_b);
#pragma unroll
    for (int o = 1; o < 32; o <<= 1) {   // two independent butterflies -> ILP
      ta += __shfl_xor(ta, o);
      tb += __shfl_xor(tb, o);
    }
    float nm = fmaxf(m, fmaxf(ta, tb));  // v_max3
    float c = __expf(m - nm);
    float pa = __expf(ta - nm);
    float pb = __expf(tb - nm);
    s = fmaf(s, c, pa + pb);
    oa = fmaf(oa, c, fmaf(pa, va0, pb * vb0));
    ob = fmaf(ob, c, fmaf(pa, va1, pb * vb1));
    m = nm;
  };

  int nfull = (jend - j0) & ~1;
  int jf = j0 + nfull;
  if (nfull) {
    unsigned cva = xl_p[(size_t)bucket[j0] * 64 + lane];
    unsigned cvb = xl_p[(size_t)bucket[j0 + 1] * 64 + lane];
    for (int j = j0 + 2; j < jf; j += 2) {
      unsigned nva = xl_p[(size_t)bucket[j] * 64 + lane];      // prefetch next pair
      unsigned nvb = xl_p[(size_t)bucket[j + 1] * 64 + lane];
      upd2(cva, cvb);
      cva = nva; cvb = nvb;
    }
    upd2(cva, cvb);
  }
  if (jf < jend) upd1(xl_p[(size_t)bucket[jf] * 64 + lane]);

  float inv = 1.f / s;
  float ra = fmaf(oa, inv, b[ch_a]);
  float rb = fmaf(ob, inv, b[ch_b]);
  h1[(size_t)node * 128 + ch_a] = ra > 0.f ? ra : __expf(ra) - 1.f;  // ELU
  h1[(size_t)node * 128 + ch_b] = rb > 0.f ? rb : __expf(rb) - 1.f;
}

// ---------- layer 2 fused: quarter-wave (16 lanes) per node ----------
// Lane l in [0,16): pair (l, l+16). Same 2-edge batching + pipeline.
__global__ void fused_layer2_k(const unsigned* __restrict__ xl_p, const unsigned* __restrict__ xr_p,
                               const int* __restrict__ off, const int* __restrict__ bucket,
                               const float* __restrict__ att, const float* __restrict__ b,
                               float* __restrict__ out, int N) {
  int node = blockIdx.x * 16 + (threadIdx.x >> 4);
  int lane = threadIdx.x & 15;
  if (node >= N) return;
  unsigned xru = xr_p[(size_t)node * 16 + lane];
  float xr_a = blo(xru), xr_b = bhi(xru);
  float att_a = att[lane], att_b = att[lane + 16];
  float m = -INFINITY, s = 0.f, oa = 0.f, ob = 0.f;
  int j0 = off[node], jend = off[node + 1];

  auto upd1 = [&](unsigned vu) {
    float va = blo(vu), vb = bhi(vu);
    float ea = va + xr_a; ea = fmaxf(ea, NEG * ea);
    float eb = vb + xr_b; eb = fmaxf(eb, NEG * eb);
    float t = fmaf(ea, att_a, eb * att_b);
#pragma unroll
    for (int o = 1; o < 16; o <<= 1) t += __shfl_xor(t, o);
    float nm = fmaxf(m, t);
    float c = __expf(m - nm), p = __expf(t - nm);
    s = fmaf(s, c, p);
    oa = fmaf(oa, c, p * va);
    ob = fmaf(ob, c, p * vb);
    m = nm;
  };

  auto upd2 = [&](unsigned ua, unsigned ub) {
    float va0 = blo(ua), va1 = bhi(ua);
    float vb0 = blo(ub), vb1 = bhi(ub);
    float ea0 = va0 + xr_a; ea0 = fmaxf(ea0, NEG * ea0);
    float ea1 = va1 + xr_b; ea1 = fmaxf(ea1, NEG * ea1);
    float eb0 = vb0 + xr_a; eb0 = fmaxf(eb0, NEG * eb0);
    float eb1 = vb1 + xr_b; eb1 = fmaxf(eb1, NEG * eb1);
    float ta = fmaf(ea0, att_a, ea1 * att_b);
    float tb = fmaf(eb0, att_a, eb1 * att_b);
#pragma unroll
    for (int o = 1; o < 16; o <<= 1) {
      ta += __shfl_xor(ta, o);
      tb += __shfl_xor(tb, o);
    }
    float nm = fmaxf(m, fmaxf(ta, tb));
    float c = __expf(m - nm);
    float pa = __expf(ta - nm);
    float pb = __expf(tb - nm);
    s = fmaf(s, c, pa + pb);
    oa = fmaf(oa, c, fmaf(pa, va0, pb * vb0));
    ob = fmaf(ob, c, fmaf(pa, va1, pb * vb1));
    m = nm;
  };

  int nfull = (jend - j0) & ~1;
  int jf = j0 + nfull;
  if (nfull) {
    unsigned cva = xl_p[(size_t)bucket[j0] * 16 + lane];
    unsigned cvb = xl_p[(size_t)bucket[j0 + 1] * 16 + lane];
    for (int j = j0 + 2; j < jf; j += 2) {
      unsigned nva = xl_p[(size_t)bucket[j] * 16 + lane];
      unsigned nvb = xl_p[(size_t)bucket[j + 1] * 16 + lane];
      upd2(cva, cvb);
      cva = nva; cvb = nvb;
    }
    upd2(cva, cvb);
  }
  if (jf < jend) upd1(xl_p[(size_t)bucket[jf] * 16 + lane]);

  float inv = 1.f / s;
  out[(size_t)node * 32 + lane]      = fmaf(oa, inv, b[lane]);
  out[(size_t)node * 32 + 16 + lane] = fmaf(ob, inv, b[lane + 16]);
}

extern "C" void kernel_launch(void* const* d_in, const int* in_sizes, int n_in,
                              void* d_out, int out_size, void* d_ws, size_t ws_size,
                              hipStream_t stream) {
  const float* x    = (const float*)d_in[0];
  const void*  ei   = d_in[1];
  const float* Wl1  = (const float*)d_in[2];
  const float* Wr1  = (const float*)d_in[3];
  const float* att1 = (const float*)d_in[4];
  const float* b1   = (const float*)d_in[5];
  const float* Wl2  = (const float*)d_in[6];
  const float* Wr2  = (const float*)d_in[7];
  const float* att2 = (const float*)d_in[8];
  const float* b2   = (const float*)d_in[9];

  const int N = in_sizes[0] / 128;
  const int E = in_sizes[1] / 2;
  const int Etot = E + N;
  float* out = (float*)d_out;
  (void)out_size; (void)n_in; (void)ws_size;

  // ---------------- workspace layout ----------------
  char* ws = (char*)d_ws;
  size_t off_b = 0;
  auto alloc = [&](size_t bytes) {
    void* p = ws + off_b;
    off_b += (bytes + 255) & ~(size_t)255;
    return p;
  };
  unsigned* xl1p   = (unsigned*)alloc((size_t)N * 64 * 4);  // packed bf16 pairs
  unsigned* xr1p   = (unsigned*)alloc((size_t)N * 64 * 4);
  float*    h1     = (float*)alloc((size_t)N * 128 * 4);
  int*      bucket = (int*)alloc((size_t)Etot * 4);
  int*      csroff = (int*)alloc((size_t)(N + 1) * 4);
  int*      cursor = (int*)alloc((size_t)N * 4);
  int*      count  = (int*)alloc((size_t)N * 4);
  int*      bsum   = (int*)alloc(256 * 4);
  int*      flag   = (int*)alloc(256);

  // layer-2 packed transforms overlay the (then-dead) xl1p region
  unsigned* xl2p = xl1p;
  unsigned* xr2p = xl1p + (size_t)N * 16;

  const int nscan = (N + 255) / 256;  // <= 256 blocks
  const int eblk = (Etot + 255) / 256;

  // ---------------- CSR build (shared by both layers) ----------------
  hipLaunchKernelGGL(detect_idx64, dim3(1), dim3(64), 0, stream, ei, N, flag);
  hipMemsetAsync(count, 0, (size_t)N * 4, stream);
  hipLaunchKernelGGL(hist_k, dim3(eblk), dim3(256), 0, stream, ei, flag, count, E, Etot);
  hipLaunchKernelGGL(scan1_k, dim3(nscan), dim3(256), 0, stream, count, bsum, N);
  hipLaunchKernelGGL(scan2_k, dim3(1), dim3(256), 0, stream, bsum, nscan);
  hipLaunchKernelGGL(scan3_k, dim3(nscan), dim3(256), 0, stream, count, bsum, csroff, cursor, N, Etot);
  hipLaunchKernelGGL(scatter_k, dim3(eblk), dim3(256), 0, stream, ei, flag, cursor, bucket, E, Etot);

  // ---------------- layer 1 ----------------
  hipLaunchKernelGGL((dual_gemm_p<128, 64, 32, 8, 64>), dim3((N + 63) / 64), dim3(256), 0, stream,
                     x, Wl1, Wr1, xl1p, xr1p, N);
  hipLaunchKernelGGL(fused_layer1_k, dim3((N + 3) / 4), dim3(256), 0, stream,
                     xl1p, xr1p, csroff, bucket, att1, b1, h1, N);

  // ---------------- layer 2 ----------------
  hipLaunchKernelGGL((dual_gemm_p<32, 128, 8, 4, 32>), dim3((N + 127) / 128), dim3(256), 0, stream,
                     h1, Wl2, Wr2, xl2p, xr2p, N);
  hipLaunchKernelGGL(fused_layer2_k, dim3((N + 15) / 16), dim3(256), 0, stream,
                     xl2p, xr2p, csroff, bucket, att2, b2, out, N);
}

// Round 8
// 251.275 us; speedup vs baseline: 1.3544x; 1.0843x over previous
//
#include <hip/hip_runtime.h>

#define NEG 0.2f

// ---------- bf16 pack/unpack (RNE) ----------
__device__ __forceinline__ float blo(unsigned u) { return __uint_as_float(u << 16); }
__device__ __forceinline__ float bhi(unsigned u) { return __uint_as_float(u & 0xffff0000u); }
__device__ __forceinline__ unsigned bpack(float a, float b) {
  unsigned ua = __float_as_uint(a), ub = __float_as_uint(b);
  unsigned ra = (ua + 0x7fffu + ((ua >> 16) & 1u)) >> 16;
  unsigned rb = (ub + 0x7fffu + ((ub >> 16) & 1u)) >> 16;
  return ra | (rb << 16);
}

// ---------- detect whether edge_index arrived as int64 or int32 ----------
__global__ void detect_idx64(const void* __restrict__ ei, int n_nodes, int* __restrict__ flag) {
  const long long* e64 = (const long long*)ei;
  long long v = e64[threadIdx.x];
  bool ok = (v >= 0 && v < (long long)n_nodes);
  unsigned long long b = __ballot(ok);
  if (threadIdx.x == 0) *flag = (b == ~0ull) ? 1 : 0;
}

__device__ __forceinline__ void get_edge(const void* __restrict__ ei, int is64, int e, int E,
                                         int& src, int& dst) {
  if (e >= E) { src = e - E; dst = e - E; return; }  // self-loops appended
  if (is64) {
    const long long* p = (const long long*)ei;
    src = (int)p[e];
    dst = (int)p[(size_t)E + e];
  } else {
    const int* p = (const int*)ei;
    src = p[e];
    dst = p[E + e];
  }
}

// ---------- CSR build: histogram -> scan -> scatter ----------
__global__ void hist_k(const void* __restrict__ ei, const int* __restrict__ flag,
                       int* __restrict__ count, int E, int Etot) {
  int e = blockIdx.x * 256 + threadIdx.x;
  if (e >= Etot) return;
  int src, dst;
  get_edge(ei, *flag, e, E, src, dst);
  (void)src;
  atomicAdd(&count[dst], 1);
}

__global__ void scan1_k(const int* __restrict__ count, int* __restrict__ bsum, int n) {
  __shared__ int sd[256];
  int i = blockIdx.x * 256 + threadIdx.x;
  sd[threadIdx.x] = (i < n) ? count[i] : 0;
  __syncthreads();
  for (int o = 128; o; o >>= 1) {
    if (threadIdx.x < o) sd[threadIdx.x] += sd[threadIdx.x + o];
    __syncthreads();
  }
  if (threadIdx.x == 0) bsum[blockIdx.x] = sd[0];
}

__global__ void scan2_k(int* __restrict__ bsum, int nb) {  // exclusive scan, 1 block, nb<=256
  __shared__ int sd[256];
  int v = (threadIdx.x < nb) ? bsum[threadIdx.x] : 0;
  sd[threadIdx.x] = v;
  __syncthreads();
  for (int o = 1; o < 256; o <<= 1) {
    int t = (threadIdx.x >= o) ? sd[threadIdx.x - o] : 0;
    __syncthreads();
    sd[threadIdx.x] += t;
    __syncthreads();
  }
  if (threadIdx.x < nb) bsum[threadIdx.x] = sd[threadIdx.x] - v;
}

__global__ void scan3_k(const int* __restrict__ count, const int* __restrict__ bsum,
                        int* __restrict__ off, int* __restrict__ cursor, int n, int etot) {
  __shared__ int sd[256];
  int i = blockIdx.x * 256 + threadIdx.x;
  int v = (i < n) ? count[i] : 0;
  sd[threadIdx.x] = v;
  __syncthreads();
  for (int o = 1; o < 256; o <<= 1) {
    int t = (threadIdx.x >= o) ? sd[threadIdx.x - o] : 0;
    __syncthreads();
    sd[threadIdx.x] += t;
    __syncthreads();
  }
  if (i < n) {
    int ex = bsum[blockIdx.x] + sd[threadIdx.x] - v;
    off[i] = ex;
    cursor[i] = ex;
  }
  if (i == 0) off[n] = etot;
}

__global__ void scatter_k(const void* __restrict__ ei, const int* __restrict__ flag,
                          int* __restrict__ cursor, int* __restrict__ bucket, int E, int Etot) {
  int e = blockIdx.x * 256 + threadIdx.x;
  if (e >= Etot) return;
  int src, dst;
  get_edge(ei, *flag, e, E, src, dst);
  int pos = atomicAdd(&cursor[dst], 1);
  bucket[pos] = src;
}

// ---------- tiled dual GEMM with packed-pair bf16 epilogue ----------
template <int C, int TM, int TCG, int RPT, int HS>
__global__ void dual_gemm_p(const float* __restrict__ X,
                            const float* __restrict__ Wl,
                            const float* __restrict__ Wr,
                            unsigned* __restrict__ xl_p, unsigned* __restrict__ xr_p, int nrows) {
  constexpr int K = 128, KT = 32, W2 = 2 * C, NPM = C / 2, PS = HS / 2;
  __shared__ float xsT[KT][TM];   // transposed X tile
  __shared__ float ws[KT][W2];    // [Wl | Wr] tile
  const int tid = threadIdx.x;
  const int tc = tid % TCG, tr = tid / TCG;
  const int row0 = blockIdx.x * TM;
  const int mat = (4 * tc) / NPM;          // 0 -> xl, 1 -> xr
  const int q0 = (4 * tc) % NPM;           // pair index within matrix
  const int col_a0 = mat * C + (q0 / PS) * HS + (q0 % PS);
  float acc[RPT][8] = {};

  for (int k0 = 0; k0 < K; k0 += KT) {
    constexpr int XF4 = TM * KT / 4 / 256;
#pragma unroll
    for (int i = 0; i < XF4; ++i) {
      int f = tid + i * 256;
      int row = f / (KT / 4), j = f % (KT / 4);
      float4 v = make_float4(0.f, 0.f, 0.f, 0.f);
      if (row0 + row < nrows) v = *(const float4*)&X[(size_t)(row0 + row) * K + k0 + 4 * j];
      xsT[4 * j + 0][row] = v.x;
      xsT[4 * j + 1][row] = v.y;
      xsT[4 * j + 2][row] = v.z;
      xsT[4 * j + 3][row] = v.w;
    }
    constexpr int WF4 = KT * C / 4 / 256;
#pragma unroll
    for (int i = 0; i < WF4; ++i) {
      int f = tid + i * 256;
      int kk = f / (C / 4), c4 = f % (C / 4);
      *(float4*)&ws[kk][c4 * 4]     = *(const float4*)&Wl[(size_t)(k0 + kk) * C + c4 * 4];
      *(float4*)&ws[kk][C + c4 * 4] = *(const float4*)&Wr[(size_t)(k0 + kk) * C + c4 * 4];
    }
    __syncthreads();
#pragma unroll 4
    for (int kk = 0; kk < KT; ++kk) {
      float xv[RPT], wv[8];
#pragma unroll
      for (int i = 0; i < RPT; i += 4) *(float4*)&xv[i] = *(const float4*)&xsT[kk][tr * RPT + i];
      *(float4*)&wv[0] = *(const float4*)&ws[kk][col_a0];
      *(float4*)&wv[4] = *(const float4*)&ws[kk][col_a0 + PS];
#pragma unroll
      for (int i = 0; i < RPT; ++i)
#pragma unroll
        for (int j = 0; j < 8; ++j) acc[i][j] = fmaf(xv[i], wv[j], acc[i][j]);
    }
    __syncthreads();
  }

  unsigned* outp = (mat == 0) ? xl_p : xr_p;
#pragma unroll
  for (int i = 0; i < RPT; ++i) {
    int row = row0 + tr * RPT + i;
    if (row >= nrows) break;
    uint4 u;
    u.x = bpack(acc[i][0], acc[i][4]);
    u.y = bpack(acc[i][1], acc[i][5]);
    u.z = bpack(acc[i][2], acc[i][6]);
    u.w = bpack(acc[i][3], acc[i][7]);
    *(uint4*)&outp[(size_t)row * NPM + q0] = u;
  }
}

// ---------- layer 1 fused: wave per node, head-split half-waves ----------
// Lane l<32: head0 pair (l, l+32); lane l>=32: head1 pair (32+l, 64+l).
// 4-edge batched online softmax, double-buffered gather (8 loads in flight).
__global__ void fused_layer1_k(const unsigned* __restrict__ xl_p, const unsigned* __restrict__ xr_p,
                               const int* __restrict__ off, const int* __restrict__ bucket,
                               const float* __restrict__ att, const float* __restrict__ b,
                               float* __restrict__ h1, int N) {
  int node = blockIdx.x * 4 + (threadIdx.x >> 6);
  int lane = threadIdx.x & 63;
  if (node >= N) return;
  int ch_a = (lane < 32) ? lane : 32 + lane;
  int ch_b = ch_a + 32;
  unsigned xru = xr_p[(size_t)node * 64 + lane];
  float xr_a = blo(xru), xr_b = bhi(xru);
  float att_a = att[ch_a], att_b = att[ch_b];
  float m = -INFINITY, s = 0.f, oa = 0.f, ob = 0.f;
  int j0 = off[node], jend = off[node + 1];

  auto upd1 = [&](unsigned vu) {
    float va = blo(vu), vb = bhi(vu);
    float ea = va + xr_a; ea = fmaxf(ea, NEG * ea);
    float eb = vb + xr_b; eb = fmaxf(eb, NEG * eb);
    float t = fmaf(ea, att_a, eb * att_b);
#pragma unroll
    for (int o = 1; o < 32; o <<= 1) t += __shfl_xor(t, o);
    float nm = fmaxf(m, t);
    float c = __expf(m - nm), p = __expf(t - nm);
    s = fmaf(s, c, p);
    oa = fmaf(oa, c, p * va);
    ob = fmaf(ob, c, p * vb);
    m = nm;
  };

  auto upd4 = [&](const unsigned* v) {
    float va[4], vb[4], t[4];
#pragma unroll
    for (int k = 0; k < 4; ++k) {
      va[k] = blo(v[k]); vb[k] = bhi(v[k]);
      float ea = va[k] + xr_a; ea = fmaxf(ea, NEG * ea);
      float eb = vb[k] + xr_b; eb = fmaxf(eb, NEG * eb);
      t[k] = fmaf(ea, att_a, eb * att_b);
    }
#pragma unroll
    for (int o = 1; o < 32; o <<= 1) {   // 4 independent butterflies -> ILP
#pragma unroll
      for (int k = 0; k < 4; ++k) t[k] += __shfl_xor(t[k], o);
    }
    float nm = fmaxf(m, fmaxf(fmaxf(t[0], t[1]), fmaxf(t[2], t[3])));
    float c  = __expf(m - nm);
    float p0 = __expf(t[0] - nm), p1 = __expf(t[1] - nm);
    float p2 = __expf(t[2] - nm), p3 = __expf(t[3] - nm);
    s  = fmaf(s, c, (p0 + p1) + (p2 + p3));
    oa = fmaf(oa, c, fmaf(p0, va[0], fmaf(p1, va[1], fmaf(p2, va[2], p3 * va[3]))));
    ob = fmaf(ob, c, fmaf(p0, vb[0], fmaf(p1, vb[1], fmaf(p2, vb[2], p3 * vb[3]))));
    m = nm;
  };

  int nb = (jend - j0) & ~3;     // multiple-of-4 part
  if (nb) {
    unsigned cv[4], nv[4];
#pragma unroll
    for (int k = 0; k < 4; ++k) cv[k] = xl_p[(size_t)bucket[j0 + k] * 64 + lane];
    for (int j = j0 + 4; j < j0 + nb; j += 4) {
#pragma unroll
      for (int k = 0; k < 4; ++k) nv[k] = xl_p[(size_t)bucket[j + k] * 64 + lane];
      upd4(cv);
#pragma unroll
      for (int k = 0; k < 4; ++k) cv[k] = nv[k];
    }
    upd4(cv);
  }
  for (int j = j0 + nb; j < jend; ++j) upd1(xl_p[(size_t)bucket[j] * 64 + lane]);

  float inv = 1.f / s;
  float ra = fmaf(oa, inv, b[ch_a]);
  float rb = fmaf(ob, inv, b[ch_b]);
  h1[(size_t)node * 128 + ch_a] = ra > 0.f ? ra : __expf(ra) - 1.f;  // ELU
  h1[(size_t)node * 128 + ch_b] = rb > 0.f ? rb : __expf(rb) - 1.f;
}

// ---------- layer 2 fused: quarter-wave (16 lanes) per node ----------
// Lane l in [0,16): pair (l, l+16). Same 4-edge batching + pipeline.
__global__ void fused_layer2_k(const unsigned* __restrict__ xl_p, const unsigned* __restrict__ xr_p,
                               const int* __restrict__ off, const int* __restrict__ bucket,
                               const float* __restrict__ att, const float* __restrict__ b,
                               float* __restrict__ out, int N) {
  int node = blockIdx.x * 16 + (threadIdx.x >> 4);
  int lane = threadIdx.x & 15;
  if (node >= N) return;
  unsigned xru = xr_p[(size_t)node * 16 + lane];
  float xr_a = blo(xru), xr_b = bhi(xru);
  float att_a = att[lane], att_b = att[lane + 16];
  float m = -INFINITY, s = 0.f, oa = 0.f, ob = 0.f;
  int j0 = off[node], jend = off[node + 1];

  auto upd1 = [&](unsigned vu) {
    float va = blo(vu), vb = bhi(vu);
    float ea = va + xr_a; ea = fmaxf(ea, NEG * ea);
    float eb = vb + xr_b; eb = fmaxf(eb, NEG * eb);
    float t = fmaf(ea, att_a, eb * att_b);
#pragma unroll
    for (int o = 1; o < 16; o <<= 1) t += __shfl_xor(t, o);
    float nm = fmaxf(m, t);
    float c = __expf(m - nm), p = __expf(t - nm);
    s = fmaf(s, c, p);
    oa = fmaf(oa, c, p * va);
    ob = fmaf(ob, c, p * vb);
    m = nm;
  };

  auto upd4 = [&](const unsigned* v) {
    float va[4], vb[4], t[4];
#pragma unroll
    for (int k = 0; k < 4; ++k) {
      va[k] = blo(v[k]); vb[k] = bhi(v[k]);
      float ea = va[k] + xr_a; ea = fmaxf(ea, NEG * ea);
      float eb = vb[k] + xr_b; eb = fmaxf(eb, NEG * eb);
      t[k] = fmaf(ea, att_a, eb * att_b);
    }
#pragma unroll
    for (int o = 1; o < 16; o <<= 1) {
#pragma unroll
      for (int k = 0; k < 4; ++k) t[k] += __shfl_xor(t[k], o);
    }
    float nm = fmaxf(m, fmaxf(fmaxf(t[0], t[1]), fmaxf(t[2], t[3])));
    float c  = __expf(m - nm);
    float p0 = __expf(t[0] - nm), p1 = __expf(t[1] - nm);
    float p2 = __expf(t[2] - nm), p3 = __expf(t[3] - nm);
    s  = fmaf(s, c, (p0 + p1) + (p2 + p3));
    oa = fmaf(oa, c, fmaf(p0, va[0], fmaf(p1, va[1], fmaf(p2, va[2], p3 * va[3]))));
    ob = fmaf(ob, c, fmaf(p0, vb[0], fmaf(p1, vb[1], fmaf(p2, vb[2], p3 * vb[3]))));
    m = nm;
  };

  int nb = (jend - j0) & ~3;
  if (nb) {
    unsigned cv[4], nv[4];
#pragma unroll
    for (int k = 0; k < 4; ++k) cv[k] = xl_p[(size_t)bucket[j0 + k] * 16 + lane];
    for (int j = j0 + 4; j < j0 + nb; j += 4) {
#pragma unroll
      for (int k = 0; k < 4; ++k) nv[k] = xl_p[(size_t)bucket[j + k] * 16 + lane];
      upd4(cv);
#pragma unroll
      for (int k = 0; k < 4; ++k) cv[k] = nv[k];
    }
    upd4(cv);
  }
  for (int j = j0 + nb; j < jend; ++j) upd1(xl_p[(size_t)bucket[j] * 16 + lane]);

  float inv = 1.f / s;
  out[(size_t)node * 32 + lane]      = fmaf(oa, inv, b[lane]);
  out[(size_t)node * 32 + 16 + lane] = fmaf(ob, inv, b[lane + 16]);
}

extern "C" void kernel_launch(void* const* d_in, const int* in_sizes, int n_in,
                              void* d_out, int out_size, void* d_ws, size_t ws_size,
                              hipStream_t stream) {
  const float* x    = (const float*)d_in[0];
  const void*  ei   = d_in[1];
  const float* Wl1  = (const float*)d_in[2];
  const float* Wr1  = (const float*)d_in[3];
  const float* att1 = (const float*)d_in[4];
  const float* b1   = (const float*)d_in[5];
  const float* Wl2  = (const float*)d_in[6];
  const float* Wr2  = (const float*)d_in[7];
  const float* att2 = (const float*)d_in[8];
  const float* b2   = (const float*)d_in[9];

  const int N = in_sizes[0] / 128;
  const int E = in_sizes[1] / 2;
  const int Etot = E + N;
  float* out = (float*)d_out;
  (void)out_size; (void)n_in; (void)ws_size;

  // ---------------- workspace layout ----------------
  char* ws = (char*)d_ws;
  size_t off_b = 0;
  auto alloc = [&](size_t bytes) {
    void* p = ws + off_b;
    off_b += (bytes + 255) & ~(size_t)255;
    return p;
  };
  unsigned* xl1p   = (unsigned*)alloc((size_t)N * 64 * 4);  // packed bf16 pairs
  unsigned* xr1p   = (unsigned*)alloc((size_t)N * 64 * 4);
  float*    h1     = (float*)alloc((size_t)N * 128 * 4);
  int*      bucket = (int*)alloc((size_t)Etot * 4);
  int*      csroff = (int*)alloc((size_t)(N + 1) * 4);
  int*      cursor = (int*)alloc((size_t)N * 4);
  int*      count  = (int*)alloc((size_t)N * 4);
  int*      bsum   = (int*)alloc(256 * 4);
  int*      flag   = (int*)alloc(256);

  // layer-2 packed transforms overlay the (then-dead) xl1p region
  unsigned* xl2p = xl1p;
  unsigned* xr2p = xl1p + (size_t)N * 16;

  const int nscan = (N + 255) / 256;  // <= 256 blocks
  const int eblk = (Etot + 255) / 256;

  // ---------------- CSR build (shared by both layers) ----------------
  hipLaunchKernelGGL(detect_idx64, dim3(1), dim3(64), 0, stream, ei, N, flag);
  hipMemsetAsync(count, 0, (size_t)N * 4, stream);
  hipLaunchKernelGGL(hist_k, dim3(eblk), dim3(256), 0, stream, ei, flag, count, E, Etot);
  hipLaunchKernelGGL(scan1_k, dim3(nscan), dim3(256), 0, stream, count, bsum, N);
  hipLaunchKernelGGL(scan2_k, dim3(1), dim3(256), 0, stream, bsum, nscan);
  hipLaunchKernelGGL(scan3_k, dim3(nscan), dim3(256), 0, stream, count, bsum, csroff, cursor, N, Etot);
  hipLaunchKernelGGL(scatter_k, dim3(eblk), dim3(256), 0, stream, ei, flag, cursor, bucket, E, Etot);

  // ---------------- layer 1 ----------------
  hipLaunchKernelGGL((dual_gemm_p<128, 64, 32, 8, 64>), dim3((N + 63) / 64), dim3(256), 0, stream,
                     x, Wl1, Wr1, xl1p, xr1p, N);
  hipLaunchKernelGGL(fused_layer1_k, dim3((N + 3) / 4), dim3(256), 0, stream,
                     xl1p, xr1p, csroff, bucket, att1, b1, h1, N);

  // ---------------- layer 2 ----------------
  hipLaunchKernelGGL((dual_gemm_p<32, 128, 8, 4, 32>), dim3((N + 127) / 128), dim3(256), 0, stream,
                     h1, Wl2, Wr2, xl2p, xr2p, N);
  hipLaunchKernelGGL(fused_layer2_k, dim3((N + 15) / 16), dim3(256), 0, stream,
                     xl2p, xr2p, csroff, bucket, att2, b2, out, N);
}

// Round 9
// 235.820 us; speedup vs baseline: 1.4432x; 1.0655x over previous
//
#include <hip/hip_runtime.h>

#define NEG 0.2f

typedef __attribute__((ext_vector_type(4))) float f32x4;
typedef __attribute__((ext_vector_type(8))) short bf16x8;

// ---------- bf16 pack/unpack (RNE) ----------
__device__ __forceinline__ float blo(unsigned u) { return __uint_as_float(u << 16); }
__device__ __forceinline__ float bhi(unsigned u) { return __uint_as_float(u & 0xffff0000u); }
__device__ __forceinline__ unsigned bpack(float a, float b) {
  unsigned ua = __float_as_uint(a), ub = __float_as_uint(b);
  unsigned ra = (ua + 0x7fffu + ((ua >> 16) & 1u)) >> 16;
  unsigned rb = (ub + 0x7fffu + ((ub >> 16) & 1u)) >> 16;
  return ra | (rb << 16);
}
__device__ __forceinline__ unsigned short b16(float a) {
  unsigned ua = __float_as_uint(a);
  return (unsigned short)((ua + 0x7fffu + ((ua >> 16) & 1u)) >> 16);
}

// ---------- detect whether edge_index arrived as int64 or int32 ----------
__global__ void detect_idx64(const void* __restrict__ ei, int n_nodes, int* __restrict__ flag) {
  const long long* e64 = (const long long*)ei;
  long long v = e64[threadIdx.x];
  bool ok = (v >= 0 && v < (long long)n_nodes);
  unsigned long long b = __ballot(ok);
  if (threadIdx.x == 0) *flag = (b == ~0ull) ? 1 : 0;
}

__device__ __forceinline__ void get_edge(const void* __restrict__ ei, int is64, int e, int E,
                                         int& src, int& dst) {
  if (e >= E) { src = e - E; dst = e - E; return; }  // self-loops appended
  if (is64) {
    const long long* p = (const long long*)ei;
    src = (int)p[e];
    dst = (int)p[(size_t)E + e];
  } else {
    const int* p = (const int*)ei;
    src = p[e];
    dst = p[E + e];
  }
}

// ---------- CSR build: histogram -> scan -> scatter ----------
__global__ void hist_k(const void* __restrict__ ei, const int* __restrict__ flag,
                       int* __restrict__ count, int E, int Etot) {
  int e = blockIdx.x * 256 + threadIdx.x;
  if (e >= Etot) return;
  int src, dst;
  get_edge(ei, *flag, e, E, src, dst);
  (void)src;
  atomicAdd(&count[dst], 1);
}

__global__ void scan1_k(const int* __restrict__ count, int* __restrict__ bsum, int n) {
  __shared__ int sd[256];
  int i = blockIdx.x * 256 + threadIdx.x;
  sd[threadIdx.x] = (i < n) ? count[i] : 0;
  __syncthreads();
  for (int o = 128; o; o >>= 1) {
    if (threadIdx.x < o) sd[threadIdx.x] += sd[threadIdx.x + o];
    __syncthreads();
  }
  if (threadIdx.x == 0) bsum[blockIdx.x] = sd[0];
}

__global__ void scan2_k(int* __restrict__ bsum, int nb) {  // exclusive scan, 1 block, nb<=256
  __shared__ int sd[256];
  int v = (threadIdx.x < nb) ? bsum[threadIdx.x] : 0;
  sd[threadIdx.x] = v;
  __syncthreads();
  for (int o = 1; o < 256; o <<= 1) {
    int t = (threadIdx.x >= o) ? sd[threadIdx.x - o] : 0;
    __syncthreads();
    sd[threadIdx.x] += t;
    __syncthreads();
  }
  if (threadIdx.x < nb) bsum[threadIdx.x] = sd[threadIdx.x] - v;
}

__global__ void scan3_k(const int* __restrict__ count, const int* __restrict__ bsum,
                        int* __restrict__ off, int* __restrict__ cursor, int n, int etot) {
  __shared__ int sd[256];
  int i = blockIdx.x * 256 + threadIdx.x;
  int v = (i < n) ? count[i] : 0;
  sd[threadIdx.x] = v;
  __syncthreads();
  for (int o = 1; o < 256; o <<= 1) {
    int t = (threadIdx.x >= o) ? sd[threadIdx.x - o] : 0;
    __syncthreads();
    sd[threadIdx.x] += t;
    __syncthreads();
  }
  if (i < n) {
    int ex = bsum[blockIdx.x] + sd[threadIdx.x] - v;
    off[i] = ex;
    cursor[i] = ex;
  }
  if (i == 0) off[n] = etot;
}

__global__ void scatter_k(const void* __restrict__ ei, const int* __restrict__ flag,
                          int* __restrict__ cursor, int* __restrict__ bucket, int E, int Etot) {
  int e = blockIdx.x * 256 + threadIdx.x;
  if (e >= Etot) return;
  int src, dst;
  get_edge(ei, *flag, e, E, src, dst);
  int pos = atomicAdd(&cursor[dst], 1);
  bucket[pos] = src;
}

// ---------- pack [Wl|Wr] (fp32 row-major [128][C]) -> WbT[col][k] bf16 ----------
__global__ void packW_k(const float* __restrict__ Wl, const float* __restrict__ Wr,
                        unsigned short* __restrict__ WbT, int C, int total) {
  int i = blockIdx.x * 256 + threadIdx.x;   // i over NCOL*128
  if (i >= total) return;
  int col = i >> 7, k = i & 127;
  float v = (col < C) ? Wl[(size_t)k * C + col] : Wr[(size_t)k * C + (col - C)];
  WbT[i] = b16(v);
}

// ---------- MFMA dual GEMM: [xl|xr] = X(fp32) @ WbT(bf16), K=128 ----------
// Block: 256 threads = 4 waves; wave computes 16 rows x NCOL cols.
// A-frag: 8 consecutive fp32 from X row (lane&15 = row, lane>>4 = k-group), cvt to bf16.
// B-frag: ushort8 16B load from WbT[col][k] (lane&15 = col).
// Output: packed bf16 pairs (c, c+HS/2) -> register-local partner frag (+HS/32).
template <int NCOL, int C, int HS>
__global__ void mfma_dual_gemm(const float* __restrict__ X, const unsigned short* __restrict__ WbT,
                               unsigned* __restrict__ xl_p, unsigned* __restrict__ xr_p, int nrows) {
  constexpr int NF = NCOL / 16;     // N-frags per wave
  constexpr int NPM = C / 2;        // packed u32 per row per matrix
  constexpr int FPM = C / 16;       // frags per matrix
  constexpr int FPH = HS / 16;      // frags per head
  constexpr int POFF = HS / 32;     // partner frag offset
  const int wave = threadIdx.x >> 6;
  const int lane = threadIdx.x & 63;
  const int row0 = blockIdx.x * 64 + wave * 16;
  const int rA = row0 + (lane & 15);
  const int rAc = (rA < nrows) ? rA : (nrows - 1);
  const int kA = (lane >> 4) * 8;
  const int colB = lane & 15;

  f32x4 acc[NF];
#pragma unroll
  for (int f = 0; f < NF; ++f) acc[f] = (f32x4){0.f, 0.f, 0.f, 0.f};

#pragma unroll
  for (int k0 = 0; k0 < 128; k0 += 32) {
    // A fragment: X[rAc][k0+kA .. +8) fp32 -> bf16x8
    const float* ax = &X[(size_t)rAc * 128 + k0 + kA];
    float4 a0 = *(const float4*)ax;
    float4 a1 = *(const float4*)(ax + 4);
    union { unsigned u[4]; bf16x8 v; } af;
    af.u[0] = bpack(a0.x, a0.y);
    af.u[1] = bpack(a0.z, a0.w);
    af.u[2] = bpack(a1.x, a1.y);
    af.u[3] = bpack(a1.z, a1.w);
#pragma unroll
    for (int nf = 0; nf < NF; ++nf) {
      union { uint4 u4; bf16x8 v; } bf;
      bf.u4 = *(const uint4*)&WbT[(size_t)(nf * 16 + colB) * 128 + k0 + kA];
      acc[nf] = __builtin_amdgcn_mfma_f32_16x16x32_bf16(af.v, bf.v, acc[nf], 0, 0, 0);
    }
  }

  // epilogue: pack pairs (c, c+HS/2) -> u32, write packed layout
#pragma unroll
  for (int mat = 0; mat < 2; ++mat) {
    unsigned* outp = mat ? xr_p : xl_p;
#pragma unroll
    for (int mf = 0; mf < FPM; ++mf) {
      constexpr int PH = FPH;  // silence unused in some instantiations
      (void)PH;
      int head = mf / FPH, hf = mf % FPH;
      if (hf >= POFF) continue;
      int f = mat * FPM + mf;
      int q = head * (HS / 2) + hf * 16 + colB;
#pragma unroll
      for (int r = 0; r < 4; ++r) {
        int row = row0 + ((lane >> 4) << 2) + r;
        if (row < nrows) outp[(size_t)row * NPM + q] = bpack(acc[f][r], acc[f + POFF][r]);
      }
    }
  }
}

// ---------- layer 1 fused: wave per node, head-split half-waves ----------
// Lane l<32: head0 pair (l, l+32); lane l>=32: head1 pair (32+l, 64+l).
// 4-edge batched online softmax, double-buffered gather.
__global__ void fused_layer1_k(const unsigned* __restrict__ xl_p, const unsigned* __restrict__ xr_p,
                               const int* __restrict__ off, const int* __restrict__ bucket,
                               const float* __restrict__ att, const float* __restrict__ b,
                               float* __restrict__ h1, int N) {
  int node = blockIdx.x * 4 + (threadIdx.x >> 6);
  int lane = threadIdx.x & 63;
  if (node >= N) return;
  int ch_a = (lane < 32) ? lane : 32 + lane;
  int ch_b = ch_a + 32;
  unsigned xru = xr_p[(size_t)node * 64 + lane];
  float xr_a = blo(xru), xr_b = bhi(xru);
  float att_a = att[ch_a], att_b = att[ch_b];
  float m = -INFINITY, s = 0.f, oa = 0.f, ob = 0.f;
  int j0 = off[node], jend = off[node + 1];

  auto upd1 = [&](unsigned vu) {
    float va = blo(vu), vb = bhi(vu);
    float ea = va + xr_a; ea = fmaxf(ea, NEG * ea);
    float eb = vb + xr_b; eb = fmaxf(eb, NEG * eb);
    float t = fmaf(ea, att_a, eb * att_b);
#pragma unroll
    for (int o = 1; o < 32; o <<= 1) t += __shfl_xor(t, o);
    float nm = fmaxf(m, t);
    float c = __expf(m - nm), p = __expf(t - nm);
    s = fmaf(s, c, p);
    oa = fmaf(oa, c, p * va);
    ob = fmaf(ob, c, p * vb);
    m = nm;
  };

  auto upd4 = [&](const unsigned* v) {
    float va[4], vb[4], t[4];
#pragma unroll
    for (int k = 0; k < 4; ++k) {
      va[k] = blo(v[k]); vb[k] = bhi(v[k]);
      float ea = va[k] + xr_a; ea = fmaxf(ea, NEG * ea);
      float eb = vb[k] + xr_b; eb = fmaxf(eb, NEG * eb);
      t[k] = fmaf(ea, att_a, eb * att_b);
    }
#pragma unroll
    for (int o = 1; o < 32; o <<= 1) {
#pragma unroll
      for (int k = 0; k < 4; ++k) t[k] += __shfl_xor(t[k], o);
    }
    float nm = fmaxf(m, fmaxf(fmaxf(t[0], t[1]), fmaxf(t[2], t[3])));
    float c  = __expf(m - nm);
    float p0 = __expf(t[0] - nm), p1 = __expf(t[1] - nm);
    float p2 = __expf(t[2] - nm), p3 = __expf(t[3] - nm);
    s  = fmaf(s, c, (p0 + p1) + (p2 + p3));
    oa = fmaf(oa, c, fmaf(p0, va[0], fmaf(p1, va[1], fmaf(p2, va[2], p3 * va[3]))));
    ob = fmaf(ob, c, fmaf(p0, vb[0], fmaf(p1, vb[1], fmaf(p2, vb[2], p3 * vb[3]))));
    m = nm;
  };

  int nb = (jend - j0) & ~3;
  if (nb) {
    unsigned cv[4], nv[4];
#pragma unroll
    for (int k = 0; k < 4; ++k) cv[k] = xl_p[(size_t)bucket[j0 + k] * 64 + lane];
    for (int j = j0 + 4; j < j0 + nb; j += 4) {
#pragma unroll
      for (int k = 0; k < 4; ++k) nv[k] = xl_p[(size_t)bucket[j + k] * 64 + lane];
      upd4(cv);
#pragma unroll
      for (int k = 0; k < 4; ++k) cv[k] = nv[k];
    }
    upd4(cv);
  }
  for (int j = j0 + nb; j < jend; ++j) upd1(xl_p[(size_t)bucket[j] * 64 + lane]);

  float inv = 1.f / s;
  float ra = fmaf(oa, inv, b[ch_a]);
  float rb = fmaf(ob, inv, b[ch_b]);
  h1[(size_t)node * 128 + ch_a] = ra > 0.f ? ra : __expf(ra) - 1.f;  // ELU
  h1[(size_t)node * 128 + ch_b] = rb > 0.f ? rb : __expf(rb) - 1.f;
}

// ---------- layer 2 fused: quarter-wave (16 lanes) per node ----------
__global__ void fused_layer2_k(const unsigned* __restrict__ xl_p, const unsigned* __restrict__ xr_p,
                               const int* __restrict__ off, const int* __restrict__ bucket,
                               const float* __restrict__ att, const float* __restrict__ b,
                               float* __restrict__ out, int N) {
  int node = blockIdx.x * 16 + (threadIdx.x >> 4);
  int lane = threadIdx.x & 15;
  if (node >= N) return;
  unsigned xru = xr_p[(size_t)node * 16 + lane];
  float xr_a = blo(xru), xr_b = bhi(xru);
  float att_a = att[lane], att_b = att[lane + 16];
  float m = -INFINITY, s = 0.f, oa = 0.f, ob = 0.f;
  int j0 = off[node], jend = off[node + 1];

  auto upd1 = [&](unsigned vu) {
    float va = blo(vu), vb = bhi(vu);
    float ea = va + xr_a; ea = fmaxf(ea, NEG * ea);
    float eb = vb + xr_b; eb = fmaxf(eb, NEG * eb);
    float t = fmaf(ea, att_a, eb * att_b);
#pragma unroll
    for (int o = 1; o < 16; o <<= 1) t += __shfl_xor(t, o);
    float nm = fmaxf(m, t);
    float c = __expf(m - nm), p = __expf(t - nm);
    s = fmaf(s, c, p);
    oa = fmaf(oa, c, p * va);
    ob = fmaf(ob, c, p * vb);
    m = nm;
  };

  auto upd4 = [&](const unsigned* v) {
    float va[4], vb[4], t[4];
#pragma unroll
    for (int k = 0; k < 4; ++k) {
      va[k] = blo(v[k]); vb[k] = bhi(v[k]);
      float ea = va[k] + xr_a; ea = fmaxf(ea, NEG * ea);
      float eb = vb[k] + xr_b; eb = fmaxf(eb, NEG * eb);
      t[k] = fmaf(ea, att_a, eb * att_b);
    }
#pragma unroll
    for (int o = 1; o < 16; o <<= 1) {
#pragma unroll
      for (int k = 0; k < 4; ++k) t[k] += __shfl_xor(t[k], o);
    }
    float nm = fmaxf(m, fmaxf(fmaxf(t[0], t[1]), fmaxf(t[2], t[3])));
    float c  = __expf(m - nm);
    float p0 = __expf(t[0] - nm), p1 = __expf(t[1] - nm);
    float p2 = __expf(t[2] - nm), p3 = __expf(t[3] - nm);
    s  = fmaf(s, c, (p0 + p1) + (p2 + p3));
    oa = fmaf(oa, c, fmaf(p0, va[0], fmaf(p1, va[1], fmaf(p2, va[2], p3 * va[3]))));
    ob = fmaf(ob, c, fmaf(p0, vb[0], fmaf(p1, vb[1], fmaf(p2, vb[2], p3 * vb[3]))));
    m = nm;
  };

  int nb = (jend - j0) & ~3;
  if (nb) {
    unsigned cv[4], nv[4];
#pragma unroll
    for (int k = 0; k < 4; ++k) cv[k] = xl_p[(size_t)bucket[j0 + k] * 16 + lane];
    for (int j = j0 + 4; j < j0 + nb; j += 4) {
#pragma unroll
      for (int k = 0; k < 4; ++k) nv[k] = xl_p[(size_t)bucket[j + k] * 16 + lane];
      upd4(cv);
#pragma unroll
      for (int k = 0; k < 4; ++k) cv[k] = nv[k];
    }
    upd4(cv);
  }
  for (int j = j0 + nb; j < jend; ++j) upd1(xl_p[(size_t)bucket[j] * 16 + lane]);

  float inv = 1.f / s;
  out[(size_t)node * 32 + lane]      = fmaf(oa, inv, b[lane]);
  out[(size_t)node * 32 + 16 + lane] = fmaf(ob, inv, b[lane + 16]);
}

extern "C" void kernel_launch(void* const* d_in, const int* in_sizes, int n_in,
                              void* d_out, int out_size, void* d_ws, size_t ws_size,
                              hipStream_t stream) {
  const float* x    = (const float*)d_in[0];
  const void*  ei   = d_in[1];
  const float* Wl1  = (const float*)d_in[2];
  const float* Wr1  = (const float*)d_in[3];
  const float* att1 = (const float*)d_in[4];
  const float* b1   = (const float*)d_in[5];
  const float* Wl2  = (const float*)d_in[6];
  const float* Wr2  = (const float*)d_in[7];
  const float* att2 = (const float*)d_in[8];
  const float* b2   = (const float*)d_in[9];

  const int N = in_sizes[0] / 128;
  const int E = in_sizes[1] / 2;
  const int Etot = E + N;
  float* out = (float*)d_out;
  (void)out_size; (void)n_in; (void)ws_size;

  // ---------------- workspace layout ----------------
  char* ws = (char*)d_ws;
  size_t off_b = 0;
  auto alloc = [&](size_t bytes) {
    void* p = ws + off_b;
    off_b += (bytes + 255) & ~(size_t)255;
    return p;
  };
  unsigned*       xl1p   = (unsigned*)alloc((size_t)N * 64 * 4);  // packed bf16 pairs
  unsigned*       xr1p   = (unsigned*)alloc((size_t)N * 64 * 4);
  float*          h1     = (float*)alloc((size_t)N * 128 * 4);
  int*            bucket = (int*)alloc((size_t)Etot * 4);
  int*            csroff = (int*)alloc((size_t)(N + 1) * 4);
  int*            cursor = (int*)alloc((size_t)N * 4);
  int*            count  = (int*)alloc((size_t)N * 4);
  int*            bsum   = (int*)alloc(256 * 4);
  int*            flag   = (int*)alloc(256);
  unsigned short* WbT1   = (unsigned short*)alloc(256 * 128 * 2);  // bf16 B^T layer1
  unsigned short* WbT2   = (unsigned short*)alloc(64 * 128 * 2);   // bf16 B^T layer2

  // layer-2 packed transforms overlay the (then-dead) xl1p region
  unsigned* xl2p = xl1p;
  unsigned* xr2p = xl1p + (size_t)N * 16;

  const int nscan = (N + 255) / 256;  // <= 256 blocks
  const int eblk = (Etot + 255) / 256;

  // ---------------- weight packing (no deps) ----------------
  hipLaunchKernelGGL(packW_k, dim3((256 * 128 + 255) / 256), dim3(256), 0, stream,
                     Wl1, Wr1, WbT1, 128, 256 * 128);
  hipLaunchKernelGGL(packW_k, dim3((64 * 128 + 255) / 256), dim3(256), 0, stream,
                     Wl2, Wr2, WbT2, 32, 64 * 128);

  // ---------------- CSR build (shared by both layers) ----------------
  hipLaunchKernelGGL(detect_idx64, dim3(1), dim3(64), 0, stream, ei, N, flag);
  hipMemsetAsync(count, 0, (size_t)N * 4, stream);
  hipLaunchKernelGGL(hist_k, dim3(eblk), dim3(256), 0, stream, ei, flag, count, E, Etot);
  hipLaunchKernelGGL(scan1_k, dim3(nscan), dim3(256), 0, stream, count, bsum, N);
  hipLaunchKernelGGL(scan2_k, dim3(1), dim3(256), 0, stream, bsum, nscan);
  hipLaunchKernelGGL(scan3_k, dim3(nscan), dim3(256), 0, stream, count, bsum, csroff, cursor, N, Etot);
  hipLaunchKernelGGL(scatter_k, dim3(eblk), dim3(256), 0, stream, ei, flag, cursor, bucket, E, Etot);

  // ---------------- layer 1 ----------------
  hipLaunchKernelGGL((mfma_dual_gemm<256, 128, 64>), dim3((N + 63) / 64), dim3(256), 0, stream,
                     x, WbT1, xl1p, xr1p, N);
  hipLaunchKernelGGL(fused_layer1_k, dim3((N + 3) / 4), dim3(256), 0, stream,
                     xl1p, xr1p, csroff, bucket, att1, b1, h1, N);

  // ---------------- layer 2 ----------------
  hipLaunchKernelGGL((mfma_dual_gemm<64, 32, 32>), dim3((N + 63) / 64), dim3(256), 0, stream,
                     h1, WbT2, xl2p, xr2p, N);
  hipLaunchKernelGGL(fused_layer2_k, dim3((N + 15) / 16), dim3(256), 0, stream,
                     xl2p, xr2p, csroff, bucket, att2, b2, out, N);
}

// Round 10
// 220.425 us; speedup vs baseline: 1.5440x; 1.0698x over previous
//
#include <hip/hip_runtime.h>

#define NEG 0.2f

typedef __attribute__((ext_vector_type(4))) float f32x4;
typedef __attribute__((ext_vector_type(8))) short bf16x8;

// ---------- bf16 pack/unpack (RNE) ----------
__device__ __forceinline__ float blo(unsigned u) { return __uint_as_float(u << 16); }
__device__ __forceinline__ float bhi(unsigned u) { return __uint_as_float(u & 0xffff0000u); }
__device__ __forceinline__ unsigned bpack(float a, float b) {
  unsigned ua = __float_as_uint(a), ub = __float_as_uint(b);
  unsigned ra = (ua + 0x7fffu + ((ua >> 16) & 1u)) >> 16;
  unsigned rb = (ub + 0x7fffu + ((ub >> 16) & 1u)) >> 16;
  return ra | (rb << 16);
}
__device__ __forceinline__ unsigned short b16(float a) {
  unsigned ua = __float_as_uint(a);
  return (unsigned short)((ua + 0x7fffu + ((ua >> 16) & 1u)) >> 16);
}

// ---------- detect whether edge_index arrived as int64 or int32 ----------
__global__ void detect_idx64(const void* __restrict__ ei, int n_nodes, int* __restrict__ flag) {
  const long long* e64 = (const long long*)ei;
  long long v = e64[threadIdx.x];
  bool ok = (v >= 0 && v < (long long)n_nodes);
  unsigned long long b = __ballot(ok);
  if (threadIdx.x == 0) *flag = (b == ~0ull) ? 1 : 0;
}

__device__ __forceinline__ void get_edge(const void* __restrict__ ei, int is64, int e, int E,
                                         int& src, int& dst) {
  if (e >= E) { src = e - E; dst = e - E; return; }  // self-loops appended
  if (is64) {
    const long long* p = (const long long*)ei;
    src = (int)p[e];
    dst = (int)p[(size_t)E + e];
  } else {
    const int* p = (const int*)ei;
    src = p[e];
    dst = p[E + e];
  }
}

// ---------- XCD-range-partitioned CSR build ----------
// Nodes split into 8 contiguous ranges; range r is handled only by blocks with
// blockIdx&7==r (round-robin block->XCD heuristic). Each XCD then touches only a
// private 1/8 slice of count/cursor/bucket -> L2-resident, full-line writebacks.
// Correct regardless of the actual block->XCD mapping (write sets are disjoint).
__global__ void hist_xcd_k(const void* __restrict__ ei, const int* __restrict__ flag,
                           int* __restrict__ count, int E, int Etot, int rsz, int N, int ce) {
  int r = blockIdx.x & 7, c = blockIdx.x >> 3;
  int lo = r * rsz, hi = min(N, lo + rsz);
  int eend = min(Etot, (c + 1) * ce);
  int is64 = *flag;
  for (int e = c * ce + threadIdx.x; e < eend; e += 256) {
    int src, dst;
    get_edge(ei, is64, e, E, src, dst);
    (void)src;
    if (dst >= lo && dst < hi) atomicAdd(&count[dst], 1);
  }
}

__global__ void scatter_xcd_k(const void* __restrict__ ei, const int* __restrict__ flag,
                              int* __restrict__ cursor, int* __restrict__ bucket,
                              int E, int Etot, int rsz, int N, int ce) {
  int r = blockIdx.x & 7, c = blockIdx.x >> 3;
  int lo = r * rsz, hi = min(N, lo + rsz);
  int eend = min(Etot, (c + 1) * ce);
  int is64 = *flag;
  for (int e = c * ce + threadIdx.x; e < eend; e += 256) {
    int src, dst;
    get_edge(ei, is64, e, E, src, dst);
    if (dst >= lo && dst < hi) {
      int pos = atomicAdd(&cursor[dst], 1);
      bucket[pos] = src;
    }
  }
}

__global__ void scan1_k(const int* __restrict__ count, int* __restrict__ bsum, int n) {
  __shared__ int sd[256];
  int i = blockIdx.x * 256 + threadIdx.x;
  sd[threadIdx.x] = (i < n) ? count[i] : 0;
  __syncthreads();
  for (int o = 128; o; o >>= 1) {
    if (threadIdx.x < o) sd[threadIdx.x] += sd[threadIdx.x + o];
    __syncthreads();
  }
  if (threadIdx.x == 0) bsum[blockIdx.x] = sd[0];
}

__global__ void scan2_k(int* __restrict__ bsum, int nb) {  // exclusive scan, 1 block, nb<=256
  __shared__ int sd[256];
  int v = (threadIdx.x < nb) ? bsum[threadIdx.x] : 0;
  sd[threadIdx.x] = v;
  __syncthreads();
  for (int o = 1; o < 256; o <<= 1) {
    int t = (threadIdx.x >= o) ? sd[threadIdx.x - o] : 0;
    __syncthreads();
    sd[threadIdx.x] += t;
    __syncthreads();
  }
  if (threadIdx.x < nb) bsum[threadIdx.x] = sd[threadIdx.x] - v;
}

__global__ void scan3_k(const int* __restrict__ count, const int* __restrict__ bsum,
                        int* __restrict__ off, int* __restrict__ cursor, int n, int etot) {
  __shared__ int sd[256];
  int i = blockIdx.x * 256 + threadIdx.x;
  int v = (i < n) ? count[i] : 0;
  sd[threadIdx.x] = v;
  __syncthreads();
  for (int o = 1; o < 256; o <<= 1) {
    int t = (threadIdx.x >= o) ? sd[threadIdx.x - o] : 0;
    __syncthreads();
    sd[threadIdx.x] += t;
    __syncthreads();
  }
  if (i < n) {
    int ex = bsum[blockIdx.x] + sd[threadIdx.x] - v;
    off[i] = ex;
    cursor[i] = ex;
  }
  if (i == 0) off[n] = etot;
}

// ---------- pack [Wl|Wr] (fp32 row-major [128][C]) -> WbT[col][k] bf16 ----------
__global__ void packW_k(const float* __restrict__ Wl, const float* __restrict__ Wr,
                        unsigned short* __restrict__ WbT, int C, int total) {
  int i = blockIdx.x * 256 + threadIdx.x;   // i over NCOL*128
  if (i >= total) return;
  int col = i >> 7, k = i & 127;
  float v = (col < C) ? Wl[(size_t)k * C + col] : Wr[(size_t)k * C + (col - C)];
  WbT[i] = b16(v);
}

// ---------- MFMA dual GEMM: [xl|xr] = X(fp32) @ WbT(bf16), K=128 ----------
template <int NCOL, int C, int HS>
__global__ void mfma_dual_gemm(const float* __restrict__ X, const unsigned short* __restrict__ WbT,
                               unsigned* __restrict__ xl_p, unsigned* __restrict__ xr_p, int nrows) {
  constexpr int NF = NCOL / 16;     // N-frags per wave
  constexpr int NPM = C / 2;        // packed u32 per row per matrix
  constexpr int FPM = C / 16;       // frags per matrix
  constexpr int FPH = HS / 16;      // frags per head
  constexpr int POFF = HS / 32;     // partner frag offset
  const int wave = threadIdx.x >> 6;
  const int lane = threadIdx.x & 63;
  const int row0 = blockIdx.x * 64 + wave * 16;
  const int rA = row0 + (lane & 15);
  const int rAc = (rA < nrows) ? rA : (nrows - 1);
  const int kA = (lane >> 4) * 8;
  const int colB = lane & 15;

  f32x4 acc[NF];
#pragma unroll
  for (int f = 0; f < NF; ++f) acc[f] = (f32x4){0.f, 0.f, 0.f, 0.f};

#pragma unroll
  for (int k0 = 0; k0 < 128; k0 += 32) {
    const float* ax = &X[(size_t)rAc * 128 + k0 + kA];
    float4 a0 = *(const float4*)ax;
    float4 a1 = *(const float4*)(ax + 4);
    union { unsigned u[4]; bf16x8 v; } af;
    af.u[0] = bpack(a0.x, a0.y);
    af.u[1] = bpack(a0.z, a0.w);
    af.u[2] = bpack(a1.x, a1.y);
    af.u[3] = bpack(a1.z, a1.w);
#pragma unroll
    for (int nf = 0; nf < NF; ++nf) {
      union { uint4 u4; bf16x8 v; } bf;
      bf.u4 = *(const uint4*)&WbT[(size_t)(nf * 16 + colB) * 128 + k0 + kA];
      acc[nf] = __builtin_amdgcn_mfma_f32_16x16x32_bf16(af.v, bf.v, acc[nf], 0, 0, 0);
    }
  }

#pragma unroll
  for (int mat = 0; mat < 2; ++mat) {
    unsigned* outp = mat ? xr_p : xl_p;
#pragma unroll
    for (int mf = 0; mf < FPM; ++mf) {
      int head = mf / FPH, hf = mf % FPH;
      if (hf >= POFF) continue;
      int f = mat * FPM + mf;
      int q = head * (HS / 2) + hf * 16 + colB;
#pragma unroll
      for (int r = 0; r < 4; ++r) {
        int row = row0 + ((lane >> 4) << 2) + r;
        if (row < nrows) outp[(size_t)row * NPM + q] = bpack(acc[f][r], acc[f + POFF][r]);
      }
    }
  }
}

// ---------- layer 1 fused: wave per node, head-split half-waves ----------
__global__ void fused_layer1_k(const unsigned* __restrict__ xl_p, const unsigned* __restrict__ xr_p,
                               const int* __restrict__ off, const int* __restrict__ bucket,
                               const float* __restrict__ att, const float* __restrict__ b,
                               float* __restrict__ h1, int N) {
  int node = blockIdx.x * 4 + (threadIdx.x >> 6);
  int lane = threadIdx.x & 63;
  if (node >= N) return;
  int ch_a = (lane < 32) ? lane : 32 + lane;
  int ch_b = ch_a + 32;
  unsigned xru = xr_p[(size_t)node * 64 + lane];
  float xr_a = blo(xru), xr_b = bhi(xru);
  float att_a = att[ch_a], att_b = att[ch_b];
  float m = -INFINITY, s = 0.f, oa = 0.f, ob = 0.f;
  int j0 = off[node], jend = off[node + 1];

  auto upd1 = [&](unsigned vu) {
    float va = blo(vu), vb = bhi(vu);
    float ea = va + xr_a; ea = fmaxf(ea, NEG * ea);
    float eb = vb + xr_b; eb = fmaxf(eb, NEG * eb);
    float t = fmaf(ea, att_a, eb * att_b);
#pragma unroll
    for (int o = 1; o < 32; o <<= 1) t += __shfl_xor(t, o);
    float nm = fmaxf(m, t);
    float c = __expf(m - nm), p = __expf(t - nm);
    s = fmaf(s, c, p);
    oa = fmaf(oa, c, p * va);
    ob = fmaf(ob, c, p * vb);
    m = nm;
  };

  auto upd4 = [&](const unsigned* v) {
    float va[4], vb[4], t[4];
#pragma unroll
    for (int k = 0; k < 4; ++k) {
      va[k] = blo(v[k]); vb[k] = bhi(v[k]);
      float ea = va[k] + xr_a; ea = fmaxf(ea, NEG * ea);
      float eb = vb[k] + xr_b; eb = fmaxf(eb, NEG * eb);
      t[k] = fmaf(ea, att_a, eb * att_b);
    }
#pragma unroll
    for (int o = 1; o < 32; o <<= 1) {
#pragma unroll
      for (int k = 0; k < 4; ++k) t[k] += __shfl_xor(t[k], o);
    }
    float nm = fmaxf(m, fmaxf(fmaxf(t[0], t[1]), fmaxf(t[2], t[3])));
    float c  = __expf(m - nm);
    float p0 = __expf(t[0] - nm), p1 = __expf(t[1] - nm);
    float p2 = __expf(t[2] - nm), p3 = __expf(t[3] - nm);
    s  = fmaf(s, c, (p0 + p1) + (p2 + p3));
    oa = fmaf(oa, c, fmaf(p0, va[0], fmaf(p1, va[1], fmaf(p2, va[2], p3 * va[3]))));
    ob = fmaf(ob, c, fmaf(p0, vb[0], fmaf(p1, vb[1], fmaf(p2, vb[2], p3 * vb[3]))));
    m = nm;
  };

  int nb = (jend - j0) & ~3;
  if (nb) {
    unsigned cv[4], nv[4];
#pragma unroll
    for (int k = 0; k < 4; ++k) cv[k] = xl_p[(size_t)bucket[j0 + k] * 64 + lane];
    for (int j = j0 + 4; j < j0 + nb; j += 4) {
#pragma unroll
      for (int k = 0; k < 4; ++k) nv[k] = xl_p[(size_t)bucket[j + k] * 64 + lane];
      upd4(cv);
#pragma unroll
      for (int k = 0; k < 4; ++k) cv[k] = nv[k];
    }
    upd4(cv);
  }
  for (int j = j0 + nb; j < jend; ++j) upd1(xl_p[(size_t)bucket[j] * 64 + lane]);

  float inv = 1.f / s;
  float ra = fmaf(oa, inv, b[ch_a]);
  float rb = fmaf(ob, inv, b[ch_b]);
  h1[(size_t)node * 128 + ch_a] = ra > 0.f ? ra : __expf(ra) - 1.f;  // ELU
  h1[(size_t)node * 128 + ch_b] = rb > 0.f ? rb : __expf(rb) - 1.f;
}

// ---------- layer 2 fused: quarter-wave (16 lanes) per node ----------
__global__ void fused_layer2_k(const unsigned* __restrict__ xl_p, const unsigned* __restrict__ xr_p,
                               const int* __restrict__ off, const int* __restrict__ bucket,
                               const float* __restrict__ att, const float* __restrict__ b,
                               float* __restrict__ out, int N) {
  int node = blockIdx.x * 16 + (threadIdx.x >> 4);
  int lane = threadIdx.x & 15;
  if (node >= N) return;
  unsigned xru = xr_p[(size_t)node * 16 + lane];
  float xr_a = blo(xru), xr_b = bhi(xru);
  float att_a = att[lane], att_b = att[lane + 16];
  float m = -INFINITY, s = 0.f, oa = 0.f, ob = 0.f;
  int j0 = off[node], jend = off[node + 1];

  auto upd1 = [&](unsigned vu) {
    float va = blo(vu), vb = bhi(vu);
    float ea = va + xr_a; ea = fmaxf(ea, NEG * ea);
    float eb = vb + xr_b; eb = fmaxf(eb, NEG * eb);
    float t = fmaf(ea, att_a, eb * att_b);
#pragma unroll
    for (int o = 1; o < 16; o <<= 1) t += __shfl_xor(t, o);
    float nm = fmaxf(m, t);
    float c = __expf(m - nm), p = __expf(t - nm);
    s = fmaf(s, c, p);
    oa = fmaf(oa, c, p * va);
    ob = fmaf(ob, c, p * vb);
    m = nm;
  };

  auto upd4 = [&](const unsigned* v) {
    float va[4], vb[4], t[4];
#pragma unroll
    for (int k = 0; k < 4; ++k) {
      va[k] = blo(v[k]); vb[k] = bhi(v[k]);
      float ea = va[k] + xr_a; ea = fmaxf(ea, NEG * ea);
      float eb = vb[k] + xr_b; eb = fmaxf(eb, NEG * eb);
      t[k] = fmaf(ea, att_a, eb * att_b);
    }
#pragma unroll
    for (int o = 1; o < 16; o <<= 1) {
#pragma unroll
      for (int k = 0; k < 4; ++k) t[k] += __shfl_xor(t[k], o);
    }
    float nm = fmaxf(m, fmaxf(fmaxf(t[0], t[1]), fmaxf(t[2], t[3])));
    float c  = __expf(m - nm);
    float p0 = __expf(t[0] - nm), p1 = __expf(t[1] - nm);
    float p2 = __expf(t[2] - nm), p3 = __expf(t[3] - nm);
    s  = fmaf(s, c, (p0 + p1) + (p2 + p3));
    oa = fmaf(oa, c, fmaf(p0, va[0], fmaf(p1, va[1], fmaf(p2, va[2], p3 * va[3]))));
    ob = fmaf(ob, c, fmaf(p0, vb[0], fmaf(p1, vb[1], fmaf(p2, vb[2], p3 * vb[3]))));
    m = nm;
  };

  int nb = (jend - j0) & ~3;
  if (nb) {
    unsigned cv[4], nv[4];
#pragma unroll
    for (int k = 0; k < 4; ++k) cv[k] = xl_p[(size_t)bucket[j0 + k] * 16 + lane];
    for (int j = j0 + 4; j < j0 + nb; j += 4) {
#pragma unroll
      for (int k = 0; k < 4; ++k) nv[k] = xl_p[(size_t)bucket[j + k] * 16 + lane];
      upd4(cv);
#pragma unroll
      for (int k = 0; k < 4; ++k) cv[k] = nv[k];
    }
    upd4(cv);
  }
  for (int j = j0 + nb; j < jend; ++j) upd1(xl_p[(size_t)bucket[j] * 16 + lane]);

  float inv = 1.f / s;
  out[(size_t)node * 32 + lane]      = fmaf(oa, inv, b[lane]);
  out[(size_t)node * 32 + 16 + lane] = fmaf(ob, inv, b[lane + 16]);
}

extern "C" void kernel_launch(void* const* d_in, const int* in_sizes, int n_in,
                              void* d_out, int out_size, void* d_ws, size_t ws_size,
                              hipStream_t stream) {
  const float* x    = (const float*)d_in[0];
  const void*  ei   = d_in[1];
  const float* Wl1  = (const float*)d_in[2];
  const float* Wr1  = (const float*)d_in[3];
  const float* att1 = (const float*)d_in[4];
  const float* b1   = (const float*)d_in[5];
  const float* Wl2  = (const float*)d_in[6];
  const float* Wr2  = (const float*)d_in[7];
  const float* att2 = (const float*)d_in[8];
  const float* b2   = (const float*)d_in[9];

  const int N = in_sizes[0] / 128;
  const int E = in_sizes[1] / 2;
  const int Etot = E + N;
  float* out = (float*)d_out;
  (void)out_size; (void)n_in; (void)ws_size;

  // ---------------- workspace layout ----------------
  char* ws = (char*)d_ws;
  size_t off_b = 0;
  auto alloc = [&](size_t bytes) {
    void* p = ws + off_b;
    off_b += (bytes + 255) & ~(size_t)255;
    return p;
  };
  unsigned*       xl1p   = (unsigned*)alloc((size_t)N * 64 * 4);  // packed bf16 pairs
  unsigned*       xr1p   = (unsigned*)alloc((size_t)N * 64 * 4);
  float*          h1     = (float*)alloc((size_t)N * 128 * 4);
  int*            bucket = (int*)alloc((size_t)Etot * 4);
  int*            csroff = (int*)alloc((size_t)(N + 1) * 4);
  int*            cursor = (int*)alloc((size_t)N * 4);
  int*            count  = (int*)alloc((size_t)N * 4);
  int*            bsum   = (int*)alloc(256 * 4);
  int*            flag   = (int*)alloc(256);
  unsigned short* WbT1   = (unsigned short*)alloc(256 * 128 * 2);  // bf16 B^T layer1
  unsigned short* WbT2   = (unsigned short*)alloc(64 * 128 * 2);   // bf16 B^T layer2

  // layer-2 packed transforms overlay the (then-dead) xl1p region
  unsigned* xl2p = xl1p;
  unsigned* xr2p = xl1p + (size_t)N * 16;

  const int nscan = (N + 255) / 256;       // <= 256 blocks
  const int rsz = (N + 7) / 8;             // nodes per XCD range
  const int nch = 256;                     // edge chunks for partitioned CSR build
  const int ce = (Etot + nch - 1) / nch;   // edges per chunk

  // ---------------- weight packing (no deps) ----------------
  hipLaunchKernelGGL(packW_k, dim3((256 * 128 + 255) / 256), dim3(256), 0, stream,
                     Wl1, Wr1, WbT1, 128, 256 * 128);
  hipLaunchKernelGGL(packW_k, dim3((64 * 128 + 255) / 256), dim3(256), 0, stream,
                     Wl2, Wr2, WbT2, 32, 64 * 128);

  // ---------------- CSR build (XCD-partitioned) ----------------
  hipLaunchKernelGGL(detect_idx64, dim3(1), dim3(64), 0, stream, ei, N, flag);
  hipMemsetAsync(count, 0, (size_t)N * 4, stream);
  hipLaunchKernelGGL(hist_xcd_k, dim3(8 * nch), dim3(256), 0, stream,
                     ei, flag, count, E, Etot, rsz, N, ce);
  hipLaunchKernelGGL(scan1_k, dim3(nscan), dim3(256), 0, stream, count, bsum, N);
  hipLaunchKernelGGL(scan2_k, dim3(1), dim3(256), 0, stream, bsum, nscan);
  hipLaunchKernelGGL(scan3_k, dim3(nscan), dim3(256), 0, stream, count, bsum, csroff, cursor, N, Etot);
  hipLaunchKernelGGL(scatter_xcd_k, dim3(8 * nch), dim3(256), 0, stream,
                     ei, flag, cursor, bucket, E, Etot, rsz, N, ce);

  // ---------------- layer 1 ----------------
  hipLaunchKernelGGL((mfma_dual_gemm<256, 128, 64>), dim3((N + 63) / 64), dim3(256), 0, stream,
                     x, WbT1, xl1p, xr1p, N);
  hipLaunchKernelGGL(fused_layer1_k, dim3((N + 3) / 4), dim3(256), 0, stream,
                     xl1p, xr1p, csroff, bucket, att1, b1, h1, N);

  // ---------------- layer 2 ----------------
  hipLaunchKernelGGL((mfma_dual_gemm<64, 32, 32>), dim3((N + 63) / 64), dim3(256), 0, stream,
                     h1, WbT2, xl2p, xr2p, N);
  hipLaunchKernelGGL(fused_layer2_k, dim3((N + 15) / 16), dim3(256), 0, stream,
                     xl2p, xr2p, csroff, bucket, att2, b2, out, N);
}

// Round 11
// 219.063 us; speedup vs baseline: 1.5536x; 1.0062x over previous
//
#include <hip/hip_runtime.h>

#define NEG 0.2f

typedef __attribute__((ext_vector_type(4))) float f32x4;
typedef __attribute__((ext_vector_type(8))) short bf16x8;

// ---------- bf16 pack/unpack (RNE) ----------
__device__ __forceinline__ float blo(unsigned u) { return __uint_as_float(u << 16); }
__device__ __forceinline__ float bhi(unsigned u) { return __uint_as_float(u & 0xffff0000u); }
__device__ __forceinline__ unsigned bpack(float a, float b) {
  unsigned ua = __float_as_uint(a), ub = __float_as_uint(b);
  unsigned ra = (ua + 0x7fffu + ((ua >> 16) & 1u)) >> 16;
  unsigned rb = (ub + 0x7fffu + ((ub >> 16) & 1u)) >> 16;
  return ra | (rb << 16);
}
__device__ __forceinline__ unsigned short b16(float a) {
  unsigned ua = __float_as_uint(a);
  return (unsigned short)((ua + 0x7fffu + ((ua >> 16) & 1u)) >> 16);
}

// 16-lane xor-butterfly reduce via ds_swizzle (pattern immediate, 3 inst/stage).
__device__ __forceinline__ float red16(float t) {
  t += __int_as_float(__builtin_amdgcn_ds_swizzle(__float_as_int(t), 0x041F));  // xor 1
  t += __int_as_float(__builtin_amdgcn_ds_swizzle(__float_as_int(t), 0x081F));  // xor 2
  t += __int_as_float(__builtin_amdgcn_ds_swizzle(__float_as_int(t), 0x101F));  // xor 4
  t += __int_as_float(__builtin_amdgcn_ds_swizzle(__float_as_int(t), 0x201F));  // xor 8
  return t;
}

// ---------- detect whether edge_index arrived as int64 or int32 ----------
__global__ void detect_idx64(const void* __restrict__ ei, int n_nodes, int* __restrict__ flag) {
  const long long* e64 = (const long long*)ei;
  long long v = e64[threadIdx.x];
  bool ok = (v >= 0 && v < (long long)n_nodes);
  unsigned long long b = __ballot(ok);
  if (threadIdx.x == 0) *flag = (b == ~0ull) ? 1 : 0;
}

__device__ __forceinline__ void get_edge(const void* __restrict__ ei, int is64, int e, int E,
                                         int& src, int& dst) {
  if (e >= E) { src = e - E; dst = e - E; return; }  // self-loops appended
  if (is64) {
    const long long* p = (const long long*)ei;
    src = (int)p[e];
    dst = (int)p[(size_t)E + e];
  } else {
    const int* p = (const int*)ei;
    src = p[e];
    dst = p[E + e];
  }
}

// ---------- XCD-range-partitioned CSR build ----------
__global__ void hist_xcd_k(const void* __restrict__ ei, const int* __restrict__ flag,
                           int* __restrict__ count, int E, int Etot, int rsz, int N, int ce) {
  int r = blockIdx.x & 7, c = blockIdx.x >> 3;
  int lo = r * rsz, hi = min(N, lo + rsz);
  int eend = min(Etot, (c + 1) * ce);
  int is64 = *flag;
  for (int e = c * ce + threadIdx.x; e < eend; e += 256) {
    int src, dst;
    get_edge(ei, is64, e, E, src, dst);
    (void)src;
    if (dst >= lo && dst < hi) atomicAdd(&count[dst], 1);
  }
}

__global__ void scatter_xcd_k(const void* __restrict__ ei, const int* __restrict__ flag,
                              int* __restrict__ cursor, int* __restrict__ bucket,
                              int E, int Etot, int rsz, int N, int ce) {
  int r = blockIdx.x & 7, c = blockIdx.x >> 3;
  int lo = r * rsz, hi = min(N, lo + rsz);
  int eend = min(Etot, (c + 1) * ce);
  int is64 = *flag;
  for (int e = c * ce + threadIdx.x; e < eend; e += 256) {
    int src, dst;
    get_edge(ei, is64, e, E, src, dst);
    if (dst >= lo && dst < hi) {
      int pos = atomicAdd(&cursor[dst], 1);
      bucket[pos] = src;
    }
  }
}

__global__ void scan1_k(const int* __restrict__ count, int* __restrict__ bsum, int n) {
  __shared__ int sd[256];
  int i = blockIdx.x * 256 + threadIdx.x;
  sd[threadIdx.x] = (i < n) ? count[i] : 0;
  __syncthreads();
  for (int o = 128; o; o >>= 1) {
    if (threadIdx.x < o) sd[threadIdx.x] += sd[threadIdx.x + o];
    __syncthreads();
  }
  if (threadIdx.x == 0) bsum[blockIdx.x] = sd[0];
}

__global__ void scan2_k(int* __restrict__ bsum, int nb) {
  __shared__ int sd[256];
  int v = (threadIdx.x < nb) ? bsum[threadIdx.x] : 0;
  sd[threadIdx.x] = v;
  __syncthreads();
  for (int o = 1; o < 256; o <<= 1) {
    int t = (threadIdx.x >= o) ? sd[threadIdx.x - o] : 0;
    __syncthreads();
    sd[threadIdx.x] += t;
    __syncthreads();
  }
  if (threadIdx.x < nb) bsum[threadIdx.x] = sd[threadIdx.x] - v;
}

__global__ void scan3_k(const int* __restrict__ count, const int* __restrict__ bsum,
                        int* __restrict__ off, int* __restrict__ cursor, int n, int etot) {
  __shared__ int sd[256];
  int i = blockIdx.x * 256 + threadIdx.x;
  int v = (i < n) ? count[i] : 0;
  sd[threadIdx.x] = v;
  __syncthreads();
  for (int o = 1; o < 256; o <<= 1) {
    int t = (threadIdx.x >= o) ? sd[threadIdx.x - o] : 0;
    __syncthreads();
    sd[threadIdx.x] += t;
    __syncthreads();
  }
  if (i < n) {
    int ex = bsum[blockIdx.x] + sd[threadIdx.x] - v;
    off[i] = ex;
    cursor[i] = ex;
  }
  if (i == 0) off[n] = etot;
}

// ---------- pack [Wl|Wr] (fp32 row-major [128][C]) -> WbT[col][k] bf16 ----------
__global__ void packW_k(const float* __restrict__ Wl, const float* __restrict__ Wr,
                        unsigned short* __restrict__ WbT, int C, int total) {
  int i = blockIdx.x * 256 + threadIdx.x;
  if (i >= total) return;
  int col = i >> 7, k = i & 127;
  float v = (col < C) ? Wl[(size_t)k * C + col] : Wr[(size_t)k * C + (col - C)];
  WbT[i] = b16(v);
}

// ---------- MFMA dual GEMM: [xl|xr] = X(fp32) @ WbT(bf16), K=128 ----------
// PAIRI=true: pair-interleaved packed layout q = 2*(pair) + head (layer 1).
// PAIRI=false: q = pair (layer 2, single head).
template <int NCOL, int C, int HS, bool PAIRI>
__global__ void mfma_dual_gemm(const float* __restrict__ X, const unsigned short* __restrict__ WbT,
                               unsigned* __restrict__ xl_p, unsigned* __restrict__ xr_p, int nrows) {
  constexpr int NF = NCOL / 16;
  constexpr int NPM = C / 2;
  constexpr int FPM = C / 16;
  constexpr int FPH = HS / 16;
  constexpr int POFF = HS / 32;
  const int wave = threadIdx.x >> 6;
  const int lane = threadIdx.x & 63;
  const int row0 = blockIdx.x * 64 + wave * 16;
  const int rA = row0 + (lane & 15);
  const int rAc = (rA < nrows) ? rA : (nrows - 1);
  const int kA = (lane >> 4) * 8;
  const int colB = lane & 15;

  f32x4 acc[NF];
#pragma unroll
  for (int f = 0; f < NF; ++f) acc[f] = (f32x4){0.f, 0.f, 0.f, 0.f};

#pragma unroll
  for (int k0 = 0; k0 < 128; k0 += 32) {
    const float* ax = &X[(size_t)rAc * 128 + k0 + kA];
    float4 a0 = *(const float4*)ax;
    float4 a1 = *(const float4*)(ax + 4);
    union { unsigned u[4]; bf16x8 v; } af;
    af.u[0] = bpack(a0.x, a0.y);
    af.u[1] = bpack(a0.z, a0.w);
    af.u[2] = bpack(a1.x, a1.y);
    af.u[3] = bpack(a1.z, a1.w);
#pragma unroll
    for (int nf = 0; nf < NF; ++nf) {
      union { uint4 u4; bf16x8 v; } bf;
      bf.u4 = *(const uint4*)&WbT[(size_t)(nf * 16 + colB) * 128 + k0 + kA];
      acc[nf] = __builtin_amdgcn_mfma_f32_16x16x32_bf16(af.v, bf.v, acc[nf], 0, 0, 0);
    }
  }

#pragma unroll
  for (int mat = 0; mat < 2; ++mat) {
    unsigned* outp = mat ? xr_p : xl_p;
#pragma unroll
    for (int mf = 0; mf < FPM; ++mf) {
      int head = mf / FPH, hf = mf % FPH;
      if (hf >= POFF) continue;
      int f = mat * FPM + mf;
      int pair = hf * 16 + colB;
      int q = PAIRI ? (2 * pair + head) : (head * (HS / 2) + pair);
#pragma unroll
      for (int r = 0; r < 4; ++r) {
        int row = row0 + ((lane >> 4) << 2) + r;
        if (row < nrows) outp[(size_t)row * NPM + q] = bpack(acc[f][r], acc[f + POFF][r]);
      }
    }
  }
}

// ---------- layer 1 fused: 16 lanes per node (4 nodes/wave), pair-interleaved rows ----------
// Lane sub holds u32s q=4sub..4sub+3: (h0 pair 2sub), (h1 pair 2sub), (h0 pair 2sub+1), (h1 pair 2sub+1).
// Per-head softmax with deferred rescale (THR=8); ds_swizzle butterfly.
__global__ void fused_layer1_k(const unsigned* __restrict__ xl_p, const unsigned* __restrict__ xr_p,
                               const int* __restrict__ off, const int* __restrict__ bucket,
                               const float* __restrict__ att, const float* __restrict__ b,
                               float* __restrict__ h1, int N) {
  int grp = threadIdx.x >> 4, sub = threadIdx.x & 15;
  int node = blockIdx.x * 16 + grp;
  if (node >= N) return;
  const int c0 = 2 * sub, c1 = 2 * sub + 1;
  uint4 xr4 = *(const uint4*)&xr_p[(size_t)node * 64 + 4 * sub];
  float xr0 = blo(xr4.x), xr1 = bhi(xr4.x);   // h0: ch c0, c0+32
  float xr2 = blo(xr4.y), xr3 = bhi(xr4.y);   // h1: ch 64+c0, 96+c0
  float xr4f = blo(xr4.z), xr5 = bhi(xr4.z);  // h0: ch c1, c1+32
  float xr6 = blo(xr4.w), xr7 = bhi(xr4.w);   // h1: ch 64+c1, 96+c1
  float at0 = att[c0], at1 = att[c0 + 32], at2 = att[64 + c0], at3 = att[96 + c0];
  float at4 = att[c1], at5 = att[c1 + 32], at6 = att[64 + c1], at7 = att[96 + c1];

  float m0 = -INFINITY, m1 = -INFINITY, s0 = 0.f, s1 = 0.f;
  float o0 = 0.f, o1 = 0.f, o2 = 0.f, o3 = 0.f, o4 = 0.f, o5 = 0.f, o6 = 0.f, o7 = 0.f;
  int j = off[node], jend = off[node + 1];

  // extract + per-head partial dot for one gathered row
  auto tpart = [&](uint4 v, float* vv, float& t0, float& t1) {
    vv[0] = blo(v.x); vv[1] = bhi(v.x); vv[2] = blo(v.y); vv[3] = bhi(v.y);
    vv[4] = blo(v.z); vv[5] = bhi(v.z); vv[6] = blo(v.w); vv[7] = bhi(v.w);
    float e0 = vv[0] + xr0;  e0 = fmaxf(e0, NEG * e0);
    float e1 = vv[1] + xr1;  e1 = fmaxf(e1, NEG * e1);
    float e2 = vv[2] + xr2;  e2 = fmaxf(e2, NEG * e2);
    float e3 = vv[3] + xr3;  e3 = fmaxf(e3, NEG * e3);
    float e4 = vv[4] + xr4f; e4 = fmaxf(e4, NEG * e4);
    float e5 = vv[5] + xr5;  e5 = fmaxf(e5, NEG * e5);
    float e6 = vv[6] + xr6;  e6 = fmaxf(e6, NEG * e6);
    float e7 = vv[7] + xr7;  e7 = fmaxf(e7, NEG * e7);
    t0 = fmaf(e0, at0, e1 * at1) + fmaf(e4, at4, e5 * at5);
    t1 = fmaf(e2, at2, e3 * at3) + fmaf(e6, at6, e7 * at7);
  };

  int b0i = bucket[j];
  int b1i = (j + 1 < jend) ? bucket[j + 1] : b0i;
  uint4 v0 = *(const uint4*)&xl_p[(size_t)b0i * 64 + 4 * sub];
  uint4 v1 = *(const uint4*)&xl_p[(size_t)b1i * 64 + 4 * sub];
  bool val1 = (j + 1 < jend);

  for (;;) {
    float va[8], vb[8], t0a, t1a, t0b, t1b;
    tpart(v0, va, t0a, t1a);
    tpart(v1, vb, t0b, t1b);
    if (!val1) { t0b = -1e30f; t1b = -1e30f; }

    // prefetch next pair (overlaps the butterflies below)
    int jn = j + 2;
    bool more = jn < jend;
    if (more) {
      int n0 = bucket[jn];
      int n1 = (jn + 1 < jend) ? bucket[jn + 1] : n0;
      v0 = *(const uint4*)&xl_p[(size_t)n0 * 64 + 4 * sub];
      v1 = *(const uint4*)&xl_p[(size_t)n1 * 64 + 4 * sub];
      val1 = (jn + 1 < jend);
    }

    t0a = red16(t0a); t1a = red16(t1a);
    t0b = red16(t0b); t1b = red16(t1b);

    float tm0 = fmaxf(t0a, t0b), tm1 = fmaxf(t1a, t1b);
    if (__any((tm0 > m0 + 8.f) || (tm1 > m1 + 8.f))) {   // rare; conservative wave-wide
      float nm0 = fmaxf(m0, tm0), nm1 = fmaxf(m1, tm1);
      float c0r = __expf(m0 - nm0), c1r = __expf(m1 - nm1);
      s0 *= c0r; s1 *= c1r;
      o0 *= c0r; o1 *= c0r; o4 *= c0r; o5 *= c0r;
      o2 *= c1r; o3 *= c1r; o6 *= c1r; o7 *= c1r;
      m0 = nm0; m1 = nm1;
    }
    float p0a = __expf(t0a - m0), p1a = __expf(t1a - m1);
    float p0b = __expf(t0b - m0), p1b = __expf(t1b - m1);
    s0 += p0a + p0b;
    s1 += p1a + p1b;
    o0 = fmaf(p0a, va[0], fmaf(p0b, vb[0], o0));
    o1 = fmaf(p0a, va[1], fmaf(p0b, vb[1], o1));
    o4 = fmaf(p0a, va[4], fmaf(p0b, vb[4], o4));
    o5 = fmaf(p0a, va[5], fmaf(p0b, vb[5], o5));
    o2 = fmaf(p1a, va[2], fmaf(p1b, vb[2], o2));
    o3 = fmaf(p1a, va[3], fmaf(p1b, vb[3], o3));
    o6 = fmaf(p1a, va[6], fmaf(p1b, vb[6], o6));
    o7 = fmaf(p1a, va[7], fmaf(p1b, vb[7], o7));
    if (!more) break;
    j = jn;
  }

  float i0 = 1.f / s0, i1 = 1.f / s1;
  auto elu = [](float r) { return r > 0.f ? r : __expf(r) - 1.f; };
  float* row = h1 + (size_t)node * 128;
  float2 w;
  w.x = elu(fmaf(o0, i0, b[c0]));       w.y = elu(fmaf(o4, i0, b[c1]));
  *(float2*)&row[c0] = w;
  w.x = elu(fmaf(o1, i0, b[c0 + 32]));  w.y = elu(fmaf(o5, i0, b[c1 + 32]));
  *(float2*)&row[c0 + 32] = w;
  w.x = elu(fmaf(o2, i1, b[64 + c0])); w.y = elu(fmaf(o6, i1, b[64 + c1]));
  *(float2*)&row[64 + c0] = w;
  w.x = elu(fmaf(o3, i1, b[96 + c0])); w.y = elu(fmaf(o7, i1, b[96 + c1]));
  *(float2*)&row[96 + c0] = w;
}

// ---------- layer 2 fused: 16 lanes per node, deferred rescale + swizzle butterfly ----------
__global__ void fused_layer2_k(const unsigned* __restrict__ xl_p, const unsigned* __restrict__ xr_p,
                               const int* __restrict__ off, const int* __restrict__ bucket,
                               const float* __restrict__ att, const float* __restrict__ b,
                               float* __restrict__ out, int N) {
  int node = blockIdx.x * 16 + (threadIdx.x >> 4);
  int lane = threadIdx.x & 15;
  if (node >= N) return;
  unsigned xru = xr_p[(size_t)node * 16 + lane];
  float xr_a = blo(xru), xr_b = bhi(xru);
  float att_a = att[lane], att_b = att[lane + 16];
  float m = -INFINITY, s = 0.f, oa = 0.f, ob = 0.f;
  int j0 = off[node], jend = off[node + 1];

  auto tpart = [&](unsigned vu, float& va, float& vb) {
    va = blo(vu); vb = bhi(vu);
    float ea = va + xr_a; ea = fmaxf(ea, NEG * ea);
    float eb = vb + xr_b; eb = fmaxf(eb, NEG * eb);
    return fmaf(ea, att_a, eb * att_b);
  };

  auto upd4 = [&](const unsigned* v, int nvalid) {
    float va0, vb0, va1, vb1, va2, vb2, va3, vb3;
    float t0 = tpart(v[0], va0, vb0);
    float t1 = tpart(v[1], va1, vb1);
    float t2 = tpart(v[2], va2, vb2);
    float t3 = tpart(v[3], va3, vb3);
    if (nvalid < 4) {
      if (nvalid <= 1) t1 = -1e30f;
      if (nvalid <= 2) t2 = -1e30f;
      t3 = -1e30f;
    }
    t0 = red16(t0); t1 = red16(t1); t2 = red16(t2); t3 = red16(t3);
    float tm = fmaxf(fmaxf(t0, t1), fmaxf(t2, t3));
    if (__any(tm > m + 8.f)) {
      float nm = fmaxf(m, tm);
      float c = __expf(m - nm);
      s *= c; oa *= c; ob *= c;
      m = nm;
    }
    float p0 = __expf(t0 - m), p1 = __expf(t1 - m);
    float p2 = __expf(t2 - m), p3 = __expf(t3 - m);
    s += (p0 + p1) + (p2 + p3);
    oa = fmaf(p0, va0, fmaf(p1, va1, fmaf(p2, va2, fmaf(p3, va3, oa))));
    ob = fmaf(p0, vb0, fmaf(p1, vb1, fmaf(p2, vb2, fmaf(p3, vb3, ob))));
  };

  unsigned cv[4], nv[4];
  int deg = jend - j0;
#pragma unroll
  for (int k = 0; k < 4; ++k) {
    int idx = j0 + ((k < deg) ? k : 0);
    cv[k] = xl_p[(size_t)bucket[idx] * 16 + lane];
  }
  int j = j0;
  for (;;) {
    int jn = j + 4;
    bool more = jn < jend;
    if (more) {
      int rem = jend - jn;
#pragma unroll
      for (int k = 0; k < 4; ++k) {
        int idx = jn + ((k < rem) ? k : 0);
        nv[k] = xl_p[(size_t)bucket[idx] * 16 + lane];
      }
    }
    int nvalid = jend - j; if (nvalid > 4) nvalid = 4;
    upd4(cv, nvalid);
    if (!more) break;
#pragma unroll
    for (int k = 0; k < 4; ++k) cv[k] = nv[k];
    j = jn;
  }

  float inv = 1.f / s;
  out[(size_t)node * 32 + lane]      = fmaf(oa, inv, b[lane]);
  out[(size_t)node * 32 + 16 + lane] = fmaf(ob, inv, b[lane + 16]);
}

extern "C" void kernel_launch(void* const* d_in, const int* in_sizes, int n_in,
                              void* d_out, int out_size, void* d_ws, size_t ws_size,
                              hipStream_t stream) {
  const float* x    = (const float*)d_in[0];
  const void*  ei   = d_in[1];
  const float* Wl1  = (const float*)d_in[2];
  const float* Wr1  = (const float*)d_in[3];
  const float* att1 = (const float*)d_in[4];
  const float* b1   = (const float*)d_in[5];
  const float* Wl2  = (const float*)d_in[6];
  const float* Wr2  = (const float*)d_in[7];
  const float* att2 = (const float*)d_in[8];
  const float* b2   = (const float*)d_in[9];

  const int N = in_sizes[0] / 128;
  const int E = in_sizes[1] / 2;
  const int Etot = E + N;
  float* out = (float*)d_out;
  (void)out_size; (void)n_in; (void)ws_size;

  // ---------------- workspace layout ----------------
  char* ws = (char*)d_ws;
  size_t off_b = 0;
  auto alloc = [&](size_t bytes) {
    void* p = ws + off_b;
    off_b += (bytes + 255) & ~(size_t)255;
    return p;
  };
  unsigned*       xl1p   = (unsigned*)alloc((size_t)N * 64 * 4);  // packed bf16 pairs
  unsigned*       xr1p   = (unsigned*)alloc((size_t)N * 64 * 4);
  float*          h1     = (float*)alloc((size_t)N * 128 * 4);
  int*            bucket = (int*)alloc((size_t)(Etot + 8) * 4);
  int*            csroff = (int*)alloc((size_t)(N + 1) * 4);
  int*            cursor = (int*)alloc((size_t)N * 4);
  int*            count  = (int*)alloc((size_t)N * 4);
  int*            bsum   = (int*)alloc(256 * 4);
  int*            flag   = (int*)alloc(256);
  unsigned short* WbT1   = (unsigned short*)alloc(256 * 128 * 2);
  unsigned short* WbT2   = (unsigned short*)alloc(64 * 128 * 2);

  // layer-2 packed transforms overlay the (then-dead) xl1p region
  unsigned* xl2p = xl1p;
  unsigned* xr2p = xl1p + (size_t)N * 16;

  const int nscan = (N + 255) / 256;
  const int rsz = (N + 7) / 8;
  const int nch = 256;
  const int ce = (Etot + nch - 1) / nch;

  // ---------------- weight packing ----------------
  hipLaunchKernelGGL(packW_k, dim3((256 * 128 + 255) / 256), dim3(256), 0, stream,
                     Wl1, Wr1, WbT1, 128, 256 * 128);
  hipLaunchKernelGGL(packW_k, dim3((64 * 128 + 255) / 256), dim3(256), 0, stream,
                     Wl2, Wr2, WbT2, 32, 64 * 128);

  // ---------------- CSR build (XCD-partitioned) ----------------
  hipLaunchKernelGGL(detect_idx64, dim3(1), dim3(64), 0, stream, ei, N, flag);
  hipMemsetAsync(count, 0, (size_t)N * 4, stream);
  hipLaunchKernelGGL(hist_xcd_k, dim3(8 * nch), dim3(256), 0, stream,
                     ei, flag, count, E, Etot, rsz, N, ce);
  hipLaunchKernelGGL(scan1_k, dim3(nscan), dim3(256), 0, stream, count, bsum, N);
  hipLaunchKernelGGL(scan2_k, dim3(1), dim3(256), 0, stream, bsum, nscan);
  hipLaunchKernelGGL(scan3_k, dim3(nscan), dim3(256), 0, stream, count, bsum, csroff, cursor, N, Etot);
  hipLaunchKernelGGL(scatter_xcd_k, dim3(8 * nch), dim3(256), 0, stream,
                     ei, flag, cursor, bucket, E, Etot, rsz, N, ce);

  // ---------------- layer 1 (pair-interleaved packed layout) ----------------
  hipLaunchKernelGGL((mfma_dual_gemm<256, 128, 64, true>), dim3((N + 63) / 64), dim3(256), 0, stream,
                     x, WbT1, xl1p, xr1p, N);
  hipLaunchKernelGGL(fused_layer1_k, dim3((N + 15) / 16), dim3(256), 0, stream,
                     xl1p, xr1p, csroff, bucket, att1, b1, h1, N);

  // ---------------- layer 2 ----------------
  hipLaunchKernelGGL((mfma_dual_gemm<64, 32, 32, false>), dim3((N + 63) / 64), dim3(256), 0, stream,
                     h1, WbT2, xl2p, xr2p, N);
  hipLaunchKernelGGL(fused_layer2_k, dim3((N + 15) / 16), dim3(256), 0, stream,
                     xl2p, xr2p, csroff, bucket, att2, b2, out, N);
}